// Round 2
// baseline (1647.432 us; speedup 1.0000x reference)
//
#include <hip/hip_runtime.h>

// ---------------------------------------------------------------------------
// TransformerEncoderLayerWithMoE on MI355X (gfx950)
// Round 6: FIX the 2-phase schedule ordering. Round 5 issued the next-tile
// stage immediately before the barrier (zero overlap: issue -> vmcnt(0)
// drain). Correct T3-minimum order (m248v2): issue stage for tile t+1 FIRST,
// then ds_read+MFMA tile t (overlapping the load latency), then one barrier.
// ---------------------------------------------------------------------------

typedef __attribute__((ext_vector_type(8))) short short8;   // 8 bf16 = 4 VGPRs
typedef __attribute__((ext_vector_type(4))) short short4v;
typedef __attribute__((ext_vector_type(4))) float floatx4;  // MFMA C/D frag

#define TOKENS 4096
#define DMODEL 1024
#define NHEADS 16
#define DHEAD  64
#define DFF    4096
#define NEXP   8
#define SEQ    1024
#define NPAIR  64   // BATCH*NHEADS

// RNE float->bf16 (finite inputs only)
__device__ inline short f2bf(float f) {
  unsigned u = __builtin_bit_cast(unsigned, f);
  unsigned r = (u + 0x7fffu + ((u >> 16) & 1u)) >> 16;
  return (short)r;
}
__device__ inline float bf2f(short h) {
  return __builtin_bit_cast(float, ((unsigned)(unsigned short)h) << 16);
}

// async 16B/lane global->LDS DMA; lds dest = wave-uniform base + lane*16
__device__ inline void gload16(const short* g, short* l) {
  __builtin_amdgcn_global_load_lds(
      (const __attribute__((address_space(1))) unsigned int*)g,
      (__attribute__((address_space(3))) unsigned int*)l, 16, 0, 0);
}

// ---------------------------------------------------------------------------
// NT GEMM: C[m,n] = scale * sum_k A[m,k]*B[n,k] (+bias[n]) (+src)
// SPLIT: A/B given as hi+lo bf16 planes; acc += Ah*Bh + Ah*Bl + Al*Bh
// EPI: 0 = bf16 store, 1 = f32 store (+optional srcadd)
// AMODE: 0 = linear rows, 1 = gathered rows via packed tokList, 2 = offset rows
// LDS layout: unpadded [rows][32] shorts, 16B chunk c of row r stored at
// chunk position c ^ (r&3) ^ ((r>>2)&3)  (bank-conflict-free, DMA-compatible)
// Double-buffered, stage-first schedule:
//   prologue: stage(0); barrier
//   loop:     stage(t+1 -> buf^1); ds_read+MFMA(buf); barrier; flip
// The barrier's implicit vmcnt(0)/lgkmcnt(0) drain is the only wait; the
// next-tile loads are in flight across the whole compute phase.
// ---------------------------------------------------------------------------
template<int BM, int BN, int WTM, int WTN, int EPI, int AMODE, bool RELU, bool SPLIT>
__global__ void __launch_bounds__((BM / WTM) * (BN / WTN) * 64)
gemm_nt(const short* __restrict__ Ab, const short* __restrict__ Abl, int lda, long sA,
        const short* __restrict__ Bb, const short* __restrict__ Bbl, int ldb, long sB,
        void* __restrict__ Cb, int ldc, long sC,
        int M, int N, int K, float scale,
        const float* __restrict__ bias, int sBias,
        const float* __restrict__ srcadd,
        const int* __restrict__ tokList,
        const int* __restrict__ counts,
        const int* __restrict__ offsets)
{
  constexpr int WROWS = BM / WTM;
  constexpr int WCOLS = BN / WTN;
  constexpr int NW = WROWS * WCOLS;
  constexpr int MT = WTM / 16;
  constexpr int NT = WTN / 16;
  constexpr int ISSA = (BM / 16) / NW;   // 1024B (16 rows) per wave-issue
  constexpr int ISSB = (BN / 16) / NW;
  constexpr int PL = SPLIT ? 2 : 1;
  constexpr int ABUF = PL * BM * 32;     // shorts per A buffer
  constexpr int BBUF = PL * BN * 32;     // shorts per B buffer

  const int z = blockIdx.z;
  int Mt = M;
  int rowbase = 0;
  const int* tl = nullptr;
  if (AMODE != 0) {
    Mt = counts[z];
    if ((int)blockIdx.x * BM >= Mt) return;
    if (AMODE == 1) tl = tokList + offsets[z];
    else rowbase = offsets[z];
  }

  const short* A = Ab + (long)z * sA;
  const short* Al = SPLIT ? (Abl + (long)z * sA) : nullptr;
  const short* B = Bb + (long)z * sB;
  const short* Bl = SPLIT ? (Bbl + (long)z * sB) : nullptr;
  const int tid = threadIdx.x;
  const int lane = tid & 63;
  const int w = tid >> 6;
  const int wrow = w % WROWS;
  const int wcol = w / WROWS;
  const int m0 = blockIdx.x * BM;
  const int n0 = blockIdx.y * BN;

  __shared__ __align__(16) short As[2 * ABUF];
  __shared__ __align__(16) short Bs[2 * BBUF];

  // staging descriptors: lane covers row (lane>>2) of its 16-row segment,
  // source chunk swizzled so frag reads are conflict-free
  const int l4 = lane >> 2;                               // row in segment
  const int lc = (lane & 3) ^ (l4 & 3) ^ ((lane >> 4) & 3); // source 16B chunk
  long agp[ISSA]; int albase[ISSA];
#pragma unroll
  for (int r = 0; r < ISSA; ++r) {
    int seg = w * ISSA + r;
    int row = seg * 16 + l4;
    int grow;
    if (AMODE == 0) grow = m0 + row;
    else if (AMODE == 1) grow = tl[min(m0 + row, Mt - 1)];
    else grow = rowbase + min(m0 + row, Mt - 1);
    agp[r] = (long)grow * lda + lc * 8;
    albase[r] = seg * 512;
  }
  long bgp[ISSB]; int blbase[ISSB];
#pragma unroll
  for (int r = 0; r < ISSB; ++r) {
    int seg = w * ISSB + r;
    int row = seg * 16 + l4;
    bgp[r] = (long)(n0 + row) * ldb + lc * 8;
    blbase[r] = seg * 512;
  }

  floatx4 acc[MT][NT];
#pragma unroll
  for (int i = 0; i < MT; ++i)
#pragma unroll
    for (int j = 0; j < NT; ++j) acc[i][j] = floatx4{0.f, 0.f, 0.f, 0.f};

  // fragment read offsets (swizzle constant per thread: rows step by 16)
  const int am = wrow * WTM + (lane & 15);
  const int bn = wcol * WTN + (lane & 15);
  const int ac = lane >> 4;
  const int aro = am * 32 + ((ac ^ (am & 3) ^ ((am >> 2) & 3)) << 3);
  const int bro = bn * 32 + ((ac ^ (bn & 3) ^ ((bn >> 2) & 3)) << 3);

  // issue all async global->LDS loads for k-tile k0 into buffer `buf`
  auto stage = [&](int buf, int k0) {
    short* Ad = &As[buf * ABUF];
    short* Bd = &Bs[buf * BBUF];
#pragma unroll
    for (int r = 0; r < ISSA; ++r) gload16(A + agp[r] + k0, Ad + albase[r]);
#pragma unroll
    for (int r = 0; r < ISSB; ++r) gload16(B + bgp[r] + k0, Bd + blbase[r]);
    if (SPLIT) {
#pragma unroll
      for (int r = 0; r < ISSA; ++r) gload16(Al + agp[r] + k0, Ad + BM * 32 + albase[r]);
#pragma unroll
      for (int r = 0; r < ISSB; ++r) gload16(Bl + bgp[r] + k0, Bd + BN * 32 + blbase[r]);
    }
  };

  // read frags from buffer `buf` and accumulate MFMAs
  auto compute = [&](int buf) {
    const short* Ar = &As[buf * ABUF];
    const short* Br = &Bs[buf * BBUF];
    short8 afh[MT], bfh[NT];
#pragma unroll
    for (int i = 0; i < MT; ++i) afh[i] = *(const short8*)&Ar[aro + i * 512];
#pragma unroll
    for (int j = 0; j < NT; ++j) bfh[j] = *(const short8*)&Br[bro + j * 512];
    if (SPLIT) {
      short8 afl[MT], bfl[NT];
#pragma unroll
      for (int i = 0; i < MT; ++i) afl[i] = *(const short8*)&Ar[BM * 32 + aro + i * 512];
#pragma unroll
      for (int j = 0; j < NT; ++j) bfl[j] = *(const short8*)&Br[BN * 32 + bro + j * 512];
#pragma unroll
      for (int i = 0; i < MT; ++i)
#pragma unroll
        for (int j = 0; j < NT; ++j) {
          acc[i][j] = __builtin_amdgcn_mfma_f32_16x16x32_bf16(afh[i], bfh[j], acc[i][j], 0, 0, 0);
          acc[i][j] = __builtin_amdgcn_mfma_f32_16x16x32_bf16(afh[i], bfl[j], acc[i][j], 0, 0, 0);
          acc[i][j] = __builtin_amdgcn_mfma_f32_16x16x32_bf16(afl[i], bfh[j], acc[i][j], 0, 0, 0);
        }
    } else {
#pragma unroll
      for (int i = 0; i < MT; ++i)
#pragma unroll
        for (int j = 0; j < NT; ++j)
          acc[i][j] = __builtin_amdgcn_mfma_f32_16x16x32_bf16(afh[i], bfh[j], acc[i][j], 0, 0, 0);
    }
  };

  const int ntile = K >> 5;           // k-steps of 32
  // prologue: stage tile 0, wait (implicit vmcnt(0) drain at barrier)
  stage(0, 0);
  __syncthreads();
  int cur = 0;
  // steady state, stage-FIRST: issue tile t+1 loads, then ds_read+MFMA of
  // tile t runs while they're in flight; single barrier drains vmcnt for
  // t+1. Buffer cur^1 was last read in iter t-1 (drained at its barrier),
  // so overwriting it here is safe.
  for (int t = 0; t < ntile - 1; ++t) {
    stage(cur ^ 1, (t + 1) << 5);     // issue next tile FIRST
    compute(cur);                     // overlap: MFMA+ds_read vs load flight
    __syncthreads();                  // vmcnt(0)+lgkmcnt(0) drain + barrier
    cur ^= 1;
  }
  compute(cur);                       // final tile, nothing left to stage

  // epilogue: C layout col=lane&15, row=(lane>>4)*4+q
  const float* bz = bias ? (bias + (long)z * sBias) : nullptr;
#pragma unroll
  for (int i = 0; i < MT; ++i) {
    int rt = wrow * WTM + i * 16 + ((lane >> 4) << 2);
#pragma unroll
    for (int j = 0; j < NT; ++j) {
      int col = n0 + wcol * WTN + j * 16 + (lane & 15);
      float badd = bz ? bz[col] : 0.f;
      floatx4 v = acc[i][j];
#pragma unroll
      for (int q = 0; q < 4; ++q) {
        int r = m0 + rt + q;
        if (AMODE != 0 && r >= Mt) break;
        long orow = (AMODE == 1) ? ((long)offsets[z] + r)
                  : (AMODE == 2) ? ((long)rowbase + r) : (long)r;
        float val = v[q] * scale + badd;
        if (RELU) val = fmaxf(val, 0.f);
        if (EPI == 0) {
          ((short*)Cb)[(long)z * sC + orow * ldc + col] = f2bf(val);
        } else {
          float* Cf = (float*)Cb + (long)z * sC;
          if (srcadd) val += srcadd[orow * ldc + col];
          Cf[orow * ldc + col] = val;
        }
      }
    }
  }
}

// f32 -> hi/lo bf16 planes
__global__ void split_bf16(const float* __restrict__ src, short* __restrict__ hi,
                           short* __restrict__ lo, int n) {
  int i = (blockIdx.x * 256 + threadIdx.x) * 4;
  if (i >= n) return;
  float4 v = *(const float4*)(src + i);
  short h0 = f2bf(v.x), h1 = f2bf(v.y), h2 = f2bf(v.z), h3 = f2bf(v.w);
  short4v oh = { h0, h1, h2, h3 };
  short4v ol = { f2bf(v.x - bf2f(h0)), f2bf(v.y - bf2f(h1)),
                 f2bf(v.z - bf2f(h2)), f2bf(v.w - bf2f(h3)) };
  *(short4v*)(hi + i) = oh;
  *(short4v*)(lo + i) = ol;
}

// f32 [R,C] -> bf16 [C,R] per batch z (R,C multiples of 64)
__global__ void transpose_bf16(const float* __restrict__ src, short* __restrict__ dst,
                               int R, int C) {
  __shared__ float t[64][65];
  long zoff = (long)blockIdx.z * R * C;
  const float* s = src + zoff;
  short* d = dst + zoff;
  int r0 = blockIdx.y * 64, c0 = blockIdx.x * 64;
  int tid = threadIdx.x;
#pragma unroll
  for (int i = 0; i < 16; ++i) {
    int flat = i * 256 + tid;
    int r = flat >> 6, c = flat & 63;
    t[r][c] = s[(long)(r0 + r) * C + c0 + c];
  }
  __syncthreads();
#pragma unroll
  for (int i = 0; i < 16; ++i) {
    int flat = i * 256 + tid;
    int c = flat >> 6, r = flat & 63;
    d[(long)(c0 + c) * R + r0 + r] = f2bf(t[r][c]);
  }
}

// qkv f32 [T,3072] -> Q,K hi/lo [pair][S][dh], Vt hi/lo [pair][dh][S]
__global__ void repack_qkv_split(const float* __restrict__ qkv,
                                 short* __restrict__ Qh, short* __restrict__ Ql,
                                 short* __restrict__ Kh, short* __restrict__ Kl,
                                 short* __restrict__ Vh, short* __restrict__ Vl) {
  long idx = (long)blockIdx.x * 256 + threadIdx.x;
  int t = (int)(idx / 3072), c = (int)(idx % 3072);
  int sec = c >> 10, within = c & 1023;
  int h = within >> 6, di = within & 63;
  int b = t >> 10, s = t & 1023;
  int g = b * NHEADS + h;
  float v = qkv[idx];
  short vh = f2bf(v);
  short vl = f2bf(v - bf2f(vh));
  if (sec == 2) {
    long vo = (long)g * 65536 + di * 1024 + s;
    Vh[vo] = vh; Vl[vo] = vl;
  } else {
    long qo = (long)g * 65536 + s * 64 + di;
    if (sec == 0) { Qh[qo] = vh; Ql[qo] = vl; }
    else          { Kh[qo] = vh; Kl[qo] = vl; }
  }
}

// row softmax on f32, write P as hi plane [0,1024) + lo plane [1024,2048) shorts
__global__ void softmax_rows_split(float* __restrict__ scores) {
  __shared__ float wred[4], wsum[4];
  long row = blockIdx.x;
  float* p = scores + row * 1024;
  int tid = threadIdx.x;
  float4 v = *(const float4*)(p + tid * 4);
  float mx = fmaxf(fmaxf(v.x, v.y), fmaxf(v.z, v.w));
  for (int m = 1; m < 64; m <<= 1) mx = fmaxf(mx, __shfl_xor(mx, m));
  if ((tid & 63) == 0) wred[tid >> 6] = mx;
  __syncthreads();
  mx = fmaxf(fmaxf(wred[0], wred[1]), fmaxf(wred[2], wred[3]));
  float e0 = expf(v.x - mx), e1 = expf(v.y - mx), e2 = expf(v.z - mx), e3 = expf(v.w - mx);
  float sm = e0 + e1 + e2 + e3;
  for (int m = 1; m < 64; m <<= 1) sm += __shfl_xor(sm, m);
  if ((tid & 63) == 0) wsum[tid >> 6] = sm;
  __syncthreads();
  float inv = 1.f / (wsum[0] + wsum[1] + wsum[2] + wsum[3]);
  float y0 = e0 * inv, y1 = e1 * inv, y2 = e2 * inv, y3 = e3 * inv;
  short h0 = f2bf(y0), h1 = f2bf(y1), h2 = f2bf(y2), h3 = f2bf(y3);
  short4v oh = { h0, h1, h2, h3 };
  short4v ol = { f2bf(y0 - bf2f(h0)), f2bf(y1 - bf2f(h1)),
                 f2bf(y2 - bf2f(h2)), f2bf(y3 - bf2f(h3)) };
  short* ps = (short*)p;
  *(short4v*)(ps + tid * 4) = oh;
  *(short4v*)(ps + 1024 + tid * 4) = ol;
}

// layer norm over rows of 1024; optional f32 and bf16 outputs
__global__ void ln_rows(const float* __restrict__ x, const float* __restrict__ g,
                        const float* __restrict__ b, float* __restrict__ of,
                        short* __restrict__ ob) {
  __shared__ float ws1[4], ws2[4];
  long row = blockIdx.x;
  const float* p = x + row * 1024;
  int tid = threadIdx.x;
  float4 v = *(const float4*)(p + tid * 4);
  float s = v.x + v.y + v.z + v.w;
  float s2 = v.x * v.x + v.y * v.y + v.z * v.z + v.w * v.w;
  for (int m = 1; m < 64; m <<= 1) { s += __shfl_xor(s, m); s2 += __shfl_xor(s2, m); }
  if ((tid & 63) == 0) { ws1[tid >> 6] = s; ws2[tid >> 6] = s2; }
  __syncthreads();
  s = ws1[0] + ws1[1] + ws1[2] + ws1[3];
  s2 = ws2[0] + ws2[1] + ws2[2] + ws2[3];
  float mean = s * (1.f / 1024.f);
  float var = s2 * (1.f / 1024.f) - mean * mean;
  float rstd = rsqrtf(var + 1e-5f);
  float4 gg = *(const float4*)(g + tid * 4);
  float4 bb = *(const float4*)(b + tid * 4);
  float y0 = (v.x - mean) * rstd * gg.x + bb.x;
  float y1 = (v.y - mean) * rstd * gg.y + bb.y;
  float y2 = (v.z - mean) * rstd * gg.z + bb.z;
  float y3 = (v.w - mean) * rstd * gg.w + bb.w;
  if (of) { float4 o = { y0, y1, y2, y3 }; *(float4*)(of + row * 1024 + tid * 4) = o; }
  if (ob) { short4v o = { f2bf(y0), f2bf(y1), f2bf(y2), f2bf(y3) }; *(short4v*)(ob + row * 1024 + tid * 4) = o; }
}

// moe combine + LN2: out = LN(accum + g1*y[pos1] + g2*y[pos2])
__global__ void combine_ln2(const float* __restrict__ accum, const float* __restrict__ y,
                            const int* __restrict__ pos1, const int* __restrict__ pos2,
                            const float* __restrict__ g1a, const float* __restrict__ g2a,
                            const float* __restrict__ gn, const float* __restrict__ bn,
                            float* __restrict__ out) {
  __shared__ float ws1[4], ws2[4];
  int t = blockIdx.x;
  int tid = threadIdx.x;
  const float* a = accum + (long)t * 1024;
  const float* y1 = y + (long)pos1[t] * 1024;
  const float* y2 = y + (long)pos2[t] * 1024;
  float G1 = g1a[t], G2 = g2a[t];
  float4 va = *(const float4*)(a + tid * 4);
  float4 v1 = *(const float4*)(y1 + tid * 4);
  float4 v2 = *(const float4*)(y2 + tid * 4);
  float x0 = va.x + G1 * v1.x + G2 * v2.x;
  float x1 = va.y + G1 * v1.y + G2 * v2.y;
  float x2 = va.z + G1 * v1.z + G2 * v2.z;
  float x3 = va.w + G1 * v1.w + G2 * v2.w;
  float s = x0 + x1 + x2 + x3;
  float s2 = x0 * x0 + x1 * x1 + x2 * x2 + x3 * x3;
  for (int m = 1; m < 64; m <<= 1) { s += __shfl_xor(s, m); s2 += __shfl_xor(s2, m); }
  if ((tid & 63) == 0) { ws1[tid >> 6] = s; ws2[tid >> 6] = s2; }
  __syncthreads();
  s = ws1[0] + ws1[1] + ws1[2] + ws1[3];
  s2 = ws2[0] + ws2[1] + ws2[2] + ws2[3];
  float mean = s * (1.f / 1024.f);
  float var = s2 * (1.f / 1024.f) - mean * mean;
  float rstd = rsqrtf(var + 1e-5f);
  float4 gg = *(const float4*)(gn + tid * 4);
  float4 bb = *(const float4*)(bn + tid * 4);
  float4 o = { (x0 - mean) * rstd * gg.x + bb.x,
               (x1 - mean) * rstd * gg.y + bb.y,
               (x2 - mean) * rstd * gg.z + bb.z,
               (x3 - mean) * rstd * gg.w + bb.w };
  *(float4*)(out + (long)t * 1024 + tid * 4) = o;
}

// router pass 1: one wave per token; NO global atomics.
__global__ void router_compute(const float* __restrict__ x, const float* __restrict__ rw,
                               const float* __restrict__ rb,
                               int* __restrict__ top1, int* __restrict__ top2,
                               float* __restrict__ g1o, float* __restrict__ g2o,
                               float* __restrict__ partialP) {
  __shared__ float pp[4][8];
  int w = threadIdx.x >> 6, lane = threadIdx.x & 63;
  int t = blockIdx.x * 4 + w;
  const float* xp = x + (long)t * 1024;
  float xv[16];
#pragma unroll
  for (int i = 0; i < 16; ++i) xv[i] = xp[lane + i * 64];
  float logit[8];
#pragma unroll
  for (int e = 0; e < 8; ++e) {
    const float* wp = rw + e * 1024;
    double a = 0.0;
#pragma unroll
    for (int i = 0; i < 16; ++i) a += (double)xv[i] * (double)wp[lane + i * 64];
    for (int m = 1; m < 64; m <<= 1) a += __shfl_xor(a, m);
    logit[e] = (float)a + rb[e];
  }
  float mx = logit[0];
#pragma unroll
  for (int e = 1; e < 8; ++e) mx = fmaxf(mx, logit[e]);
  float pe[8], sum = 0.f;
#pragma unroll
  for (int e = 0; e < 8; ++e) { pe[e] = expf(logit[e] - mx); sum += pe[e]; }
  float inv = 1.f / sum;
#pragma unroll
  for (int e = 0; e < 8; ++e) pe[e] *= inv;
  int i1 = 0;
#pragma unroll
  for (int e = 1; e < 8; ++e) if (pe[e] > pe[i1]) i1 = e;
  int i2 = (i1 == 0) ? 1 : 0;
#pragma unroll
  for (int e = 0; e < 8; ++e) if (e != i1 && pe[e] > pe[i2]) i2 = e;
  float denom = pe[i1] + pe[i2];
  if (lane == 0) {
    top1[t] = i1; top2[t] = i2;
    g1o[t] = pe[i1] / denom; g2o[t] = pe[i2] / denom;
#pragma unroll
    for (int e = 0; e < 8; ++e) pp[w][e] = pe[e];
  }
  __syncthreads();
  if (threadIdx.x < 8) {
    partialP[(long)blockIdx.x * 8 + threadIdx.x] =
        pp[0][threadIdx.x] + pp[1][threadIdx.x] + pp[2][threadIdx.x] + pp[3][threadIdx.x];
  }
}

// router pass 2 (ONE block, 1024 threads): probsum reduce, counting-sort
// tokens into packed per-expert lists (contention-free), lb loss.
__global__ void __launch_bounds__(1024) router_finalize(
    const float* __restrict__ partialP,
    const int* __restrict__ top1, const int* __restrict__ top2,
    int* __restrict__ counts, int* __restrict__ eoff_out,
    int* __restrict__ tokList, int* __restrict__ pos1, int* __restrict__ pos2,
    float* __restrict__ lb_out) {
  __shared__ float redP[16][8];
  __shared__ int wtot[16][8];
  __shared__ int tot[8], eoff[8];
  __shared__ float psum[8];
  int tid = threadIdx.x;
  int lane = tid & 63, wv = tid >> 6;

  float p[8];
#pragma unroll
  for (int e = 0; e < 8; ++e) p[e] = partialP[(long)tid * 8 + e];
  for (int m = 1; m < 64; m <<= 1)
#pragma unroll
    for (int e = 0; e < 8; ++e) p[e] += __shfl_xor(p[e], m);
  if (lane == 0)
#pragma unroll
    for (int e = 0; e < 8; ++e) redP[wv][e] = p[e];

  int c[8] = {0, 0, 0, 0, 0, 0, 0, 0};
  int expid[8];
#pragma unroll
  for (int j = 0; j < 8; ++j) {
    int i = tid * 8 + j;
    int t = i >> 1;
    int e = (i & 1) ? top2[t] : top1[t];
    expid[j] = e;
    c[e]++;
  }
  int inc[8];
#pragma unroll
  for (int e = 0; e < 8; ++e) inc[e] = c[e];
  for (int d = 1; d < 64; d <<= 1) {
#pragma unroll
    for (int e = 0; e < 8; ++e) {
      int o = __shfl_up(inc[e], d);
      if (lane >= d) inc[e] += o;
    }
  }
  if (lane == 63)
#pragma unroll
    for (int e = 0; e < 8; ++e) wtot[wv][e] = inc[e];
  __syncthreads();
  if (tid < 8) {
    int run = 0;
#pragma unroll
    for (int w = 0; w < 16; ++w) { int v = wtot[w][tid]; wtot[w][tid] = run; run += v; }
    tot[tid] = run;
    float s = 0.f;
#pragma unroll
    for (int w = 0; w < 16; ++w) s += redP[w][tid];
    psum[tid] = s;
  }
  __syncthreads();
  if (tid == 0) {
    int off = 0;
#pragma unroll
    for (int e = 0; e < 8; ++e) { eoff[e] = off; off += tot[e]; }
  }
  __syncthreads();
  int base[8], c2[8] = {0, 0, 0, 0, 0, 0, 0, 0};
#pragma unroll
  for (int e = 0; e < 8; ++e) base[e] = eoff[e] + wtot[wv][e] + inc[e] - c[e];
#pragma unroll
  for (int j = 0; j < 8; ++j) {
    int i = tid * 8 + j;
    int t = i >> 1;
    int e = expid[j];
    int dest = base[e] + c2[e]++;
    tokList[dest] = t;
    if (i & 1) pos2[t] = dest; else pos1[t] = dest;
  }
  if (tid < 8) { counts[tid] = tot[tid]; eoff_out[tid] = eoff[tid]; }
  if (tid == 0) {
    float lb = 0.f;
#pragma unroll
    for (int e = 0; e < 8; ++e)
      lb += ((float)tot[e] / 8192.f) * (psum[e] / 4096.f);
    *lb_out = 8.f * lb;
  }
}

__global__ void sentinel_kernel(float* out, int n) {
  if (threadIdx.x == 0) { out[0] = 1e9f; out[n - 1] = 1e9f; }
}

// ---------------------------------------------------------------------------
extern "C" void kernel_launch(void* const* d_in, const int* in_sizes, int n_in,
                              void* d_out, int out_size, void* d_ws, size_t ws_size,
                              hipStream_t stream) {
  const float* src        = (const float*)d_in[0];
  const float* in_proj_w  = (const float*)d_in[1];
  const float* in_proj_b  = (const float*)d_in[2];
  const float* out_proj_w = (const float*)d_in[3];
  const float* out_proj_b = (const float*)d_in[4];
  const float* ln1_g      = (const float*)d_in[5];
  const float* ln1_b      = (const float*)d_in[6];
  const float* router_w   = (const float*)d_in[7];
  const float* router_b   = (const float*)d_in[8];
  const float* w1         = (const float*)d_in[9];
  const float* b1         = (const float*)d_in[10];
  const float* w2         = (const float*)d_in[11];
  const float* b2         = (const float*)d_in[12];
  const float* ln2_g      = (const float*)d_in[13];
  const float* ln2_b      = (const float*)d_in[14];
  float* out = (float*)d_out;

  char* ws = (char*)d_ws;
  size_t off = 0;
  auto alloc = [&](size_t bytes) -> char* {
    char* p = ws + off;
    off += (bytes + 255) & ~(size_t)255;
    return p;
  };
  // big block: Q/K/V hi+lo planes during attention; w1t/w2t after
  char*  blockW = alloc(8ll * (DFF * DMODEL + DMODEL * DFF) * 2);  // 128MB
  short* Qh = (short*)(blockW + 0ll  * 1024 * 1024);
  short* Ql = (short*)(blockW + 8ll  * 1024 * 1024);
  short* Kh = (short*)(blockW + 16ll * 1024 * 1024);
  short* Kl = (short*)(blockW + 24ll * 1024 * 1024);
  short* Vh = (short*)(blockW + 32ll * 1024 * 1024);
  short* Vl = (short*)(blockW + 40ll * 1024 * 1024);
  short* w1t = (short*)blockW;                                      // [E][dff][d]
  short* w2t = (short*)(blockW + 8ll * DFF * DMODEL * 2);           // [E][d][dff]
  short* winh  = (short*)alloc(3072ll * 1024 * 2);
  short* winl  = (short*)alloc(3072ll * 1024 * 2);
  short* wouth = (short*)alloc(1024ll * 1024 * 2);
  short* woutl = (short*)alloc(1024ll * 1024 * 2);
  short* xh    = (short*)alloc((long)TOKENS * DMODEL * 2);
  short* xl    = (short*)alloc((long)TOKENS * DMODEL * 2);
  char*  reg1  = alloc((long)TOKENS * 3072 * 4);     // 48MB: qkv f32 -> O planes/x1 -> y
  float* qkvf  = (float*)reg1;
  float* Of32  = (float*)reg1;
  short* Ohi   = (short*)(reg1 + 16ll * 1024 * 1024);
  short* Olo   = (short*)(reg1 + 24ll * 1024 * 1024);
  float* x1    = (float*)(reg1 + 32ll * 1024 * 1024);
  float* y     = (float*)reg1;                       // packed expert outputs [8192,1024] f32
  char*  reg2  = alloc(16ll * 1024 * 1024 * 4);      // 64MB: scores chunk -> h
  float* scores = (float*)reg2;
  short* h      = (short*)reg2;
  short* x1nbf = (short*)alloc((long)TOKENS * DMODEL * 2);
  float* accum = (float*)alloc((long)TOKENS * DMODEL * 4);
  float* partialP = (float*)alloc(1024 * 8 * 4);
  int*   top1   = (int*)alloc(TOKENS * 4);
  int*   top2   = (int*)alloc(TOKENS * 4);
  float* g1a    = (float*)alloc(TOKENS * 4);
  float* g2a    = (float*)alloc(TOKENS * 4);
  int*   pos1   = (int*)alloc(TOKENS * 4);
  int*   pos2   = (int*)alloc(TOKENS * 4);
  int*   counts = (int*)alloc(32);
  int*   eoff   = (int*)alloc(32);
  int*   tokList = (int*)alloc(2 * TOKENS * 4);
  size_t needed = off;

  if (ws_size < needed) {
    sentinel_kernel<<<1, 64, 0, stream>>>(out, out_size);
    return;
  }

  // splits of f32 inputs
  split_bf16<<<3072 * 1024 / 1024, 256, 0, stream>>>(in_proj_w, winh, winl, 3072 * 1024);
  split_bf16<<<1024 * 1024 / 1024, 256, 0, stream>>>(out_proj_w, wouth, woutl, 1024 * 1024);
  split_bf16<<<TOKENS * DMODEL / 1024, 256, 0, stream>>>(src, xh, xl, TOKENS * DMODEL);

  // QKV projection (split): qkv f32 = x @ win^T + b
  gemm_nt<128, 128, 64, 64, 1, 0, false, true><<<dim3(32, 24, 1), 256, 0, stream>>>(
      xh, xl, 1024, 0, winh, winl, 1024, 0, qkvf, 3072, 0,
      TOKENS, 3072, 1024, 1.f, in_proj_b, 0, nullptr, nullptr, nullptr, nullptr);
  repack_qkv_split<<<(int)((long)TOKENS * 3072 / 256), 256, 0, stream>>>(qkvf, Qh, Ql, Kh, Kl, Vh, Vl);

  // attention, chunked by batch (16 pairs per chunk)
  for (int c = 0; c < 4; ++c) {
    long co = (long)c * 16 * 65536;
    gemm_nt<128, 128, 64, 64, 1, 0, false, true><<<dim3(8, 8, 16), 256, 0, stream>>>(
        Qh + co, Ql + co, 64, 65536, Kh + co, Kl + co, 64, 65536, scores, 1024, 1048576,
        1024, 1024, 64, 0.125f, nullptr, 0, nullptr, nullptr, nullptr, nullptr);
    softmax_rows_split<<<16 * 1024, 256, 0, stream>>>(scores);
    // P(hi/lo in place, pitch 2048 shorts) @ V^T -> O f32
    gemm_nt<128, 64, 64, 32, 1, 0, false, true><<<dim3(8, 1, 16), 256, 0, stream>>>(
        (const short*)scores, (const short*)scores + 1024, 2048, 2097152,
        Vh + co, Vl + co, 1024, 65536,
        Of32 + (long)c * 1048576, 1024, 64,
        1024, 64, 1024, 1.f, nullptr, 0, nullptr, nullptr, nullptr, nullptr);
  }

  // expert weight transposes now (blockW's Q/K/V no longer needed)
  transpose_bf16<<<dim3(DFF / 64, DMODEL / 64, 8), 256, 0, stream>>>(w1, w1t, DMODEL, DFF);
  transpose_bf16<<<dim3(DMODEL / 64, DFF / 64, 8), 256, 0, stream>>>(w2, w2t, DFF, DMODEL);

  // split O, then out-projection (split) + bias + residual(src) -> x1 f32
  split_bf16<<<TOKENS * DMODEL / 1024, 256, 0, stream>>>(Of32, Ohi, Olo, TOKENS * DMODEL);
  gemm_nt<128, 128, 64, 64, 1, 0, false, true><<<dim3(32, 8, 1), 256, 0, stream>>>(
      Ohi, Olo, 1024, 0, wouth, woutl, 1024, 0, x1, 1024, 0,
      TOKENS, 1024, 1024, 1.f, out_proj_b, 0, src, nullptr, nullptr, nullptr);

  // LN1 -> accum (f32 residual base) + x1nbf (bf16 expert input)
  ln_rows<<<TOKENS, 256, 0, stream>>>(x1, ln1_g, ln1_b, accum, x1nbf);

  // router (atomic-free)
  router_compute<<<TOKENS / 4, 256, 0, stream>>>(accum, router_w, router_b,
                                                 top1, top2, g1a, g2a, partialP);
  router_finalize<<<1, 1024, 0, stream>>>(partialP, top1, top2, counts, eoff,
                                          tokList, pos1, pos2, out + (out_size - 1));

  // expert GEMM1: h = relu(gather(x1nbf) @ w1t[e]^T + b1[e]) (packed bf16)
  gemm_nt<128, 128, 64, 64, 0, 1, true, false><<<dim3(32, 32, 8), 256, 0, stream>>>(
      x1nbf, nullptr, 1024, 0, w1t, nullptr, 1024, (long)DFF * DMODEL, h, DFF, 0,
      0, DFF, 1024, 1.f, b1, DFF, nullptr, tokList, counts, eoff);

  // expert GEMM2: y[packed] = h @ w2t[e]^T + b2[e]  (f32 store, no atomics)
  gemm_nt<128, 128, 64, 64, 1, 2, false, false><<<dim3(32, 8, 8), 256, 0, stream>>>(
      h, nullptr, DFF, 0, w2t, nullptr, DFF, (long)DMODEL * DFF, y, 1024, 0,
      0, DMODEL, DFF, 1.f, b2, DMODEL, nullptr, tokList, counts, eoff);

  // combine + LN2 -> final output
  combine_ln2<<<TOKENS, 256, 0, stream>>>(accum, y, pos1, pos2, g1a, g2a,
                                          ln2_g, ln2_b, out);
}

// Round 3
// 1542.129 us; speedup vs baseline: 1.0683x; 1.0683x over previous
//
#include <hip/hip_runtime.h>

// ---------------------------------------------------------------------------
// TransformerEncoderLayerWithMoE on MI355X (gfx950)
// Round 7: depth-2 software pipeline with COUNTED vmcnt + raw s_barrier
// (T4/m218). R0-R2 all had a vmcnt(0) drain per k-step (explicit via
// __syncthreads or compiler-inserted), exposing full load latency every
// 32-wide k-step (MfmaUtil ~7.5%). Now two tiles are always in flight:
//   prologue: stage(tile0), stage(tile1)
//   iter t:   s_waitcnt vmcnt(LDSL)  // tile t landed; t+1 still in flight
//             s_barrier; compute(buf); s_barrier; stage(buf, t+2)
// No drain-to-zero in the main loop; loads get ~2 iterations to land.
// ---------------------------------------------------------------------------

typedef __attribute__((ext_vector_type(8))) short short8;   // 8 bf16 = 4 VGPRs
typedef __attribute__((ext_vector_type(4))) short short4v;
typedef __attribute__((ext_vector_type(4))) float floatx4;  // MFMA C/D frag

#define TOKENS 4096
#define DMODEL 1024
#define NHEADS 16
#define DHEAD  64
#define DFF    4096
#define NEXP   8
#define SEQ    1024
#define NPAIR  64   // BATCH*NHEADS

// RNE float->bf16 (finite inputs only)
__device__ inline short f2bf(float f) {
  unsigned u = __builtin_bit_cast(unsigned, f);
  unsigned r = (u + 0x7fffu + ((u >> 16) & 1u)) >> 16;
  return (short)r;
}
__device__ inline float bf2f(short h) {
  return __builtin_bit_cast(float, ((unsigned)(unsigned short)h) << 16);
}

// async 16B/lane global->LDS DMA; lds dest = wave-uniform base + lane*16
__device__ inline void gload16(const short* g, short* l) {
  __builtin_amdgcn_global_load_lds(
      (const __attribute__((address_space(1))) unsigned int*)g,
      (__attribute__((address_space(3))) unsigned int*)l, 16, 0, 0);
}

// counted vector-memory wait (immediate must be literal in the asm string)
template<int N> __device__ inline void wait_vmcnt() {
  static_assert(N == 0 || N == 3 || N == 4 || N == 6 || N == 8 || N == 12 || N == 16,
                "unsupported vmcnt literal");
  if constexpr (N == 0)       asm volatile("s_waitcnt vmcnt(0)" ::: "memory");
  else if constexpr (N == 3)  asm volatile("s_waitcnt vmcnt(3)" ::: "memory");
  else if constexpr (N == 4)  asm volatile("s_waitcnt vmcnt(4)" ::: "memory");
  else if constexpr (N == 6)  asm volatile("s_waitcnt vmcnt(6)" ::: "memory");
  else if constexpr (N == 8)  asm volatile("s_waitcnt vmcnt(8)" ::: "memory");
  else if constexpr (N == 12) asm volatile("s_waitcnt vmcnt(12)" ::: "memory");
  else if constexpr (N == 16) asm volatile("s_waitcnt vmcnt(16)" ::: "memory");
}

// ---------------------------------------------------------------------------
// NT GEMM: C[m,n] = scale * sum_k A[m,k]*B[n,k] (+bias[n]) (+src)
// SPLIT: A/B given as hi+lo bf16 planes; acc += Ah*Bh + Ah*Bl + Al*Bh
// EPI: 0 = bf16 store, 1 = f32 store (+optional srcadd)
// AMODE: 0 = linear rows, 1 = gathered rows via packed tokList, 2 = offset rows
// LDS layout: unpadded [rows][32] shorts, 16B chunk c of row r stored at
// chunk position c ^ (r&3) ^ ((r>>2)&3)  (bank-conflict-free, DMA-compatible)
// Depth-2 pipeline, counted vmcnt, raw barriers (see header comment).
// ---------------------------------------------------------------------------
template<int BM, int BN, int WTM, int WTN, int EPI, int AMODE, bool RELU, bool SPLIT>
__global__ void __launch_bounds__((BM / WTM) * (BN / WTN) * 64)
gemm_nt(const short* __restrict__ Ab, const short* __restrict__ Abl, int lda, long sA,
        const short* __restrict__ Bb, const short* __restrict__ Bbl, int ldb, long sB,
        void* __restrict__ Cb, int ldc, long sC,
        int M, int N, int K, float scale,
        const float* __restrict__ bias, int sBias,
        const float* __restrict__ srcadd,
        const int* __restrict__ tokList,
        const int* __restrict__ counts,
        const int* __restrict__ offsets)
{
  constexpr int WROWS = BM / WTM;
  constexpr int WCOLS = BN / WTN;
  constexpr int NW = WROWS * WCOLS;
  constexpr int MT = WTM / 16;
  constexpr int NT = WTN / 16;
  constexpr int ISSA = (BM / 16) / NW;   // 1024B (16 rows) per wave-issue
  constexpr int ISSB = (BN / 16) / NW;
  constexpr int PL = SPLIT ? 2 : 1;
  constexpr int ABUF = PL * BM * 32;     // shorts per A buffer
  constexpr int BBUF = PL * BN * 32;     // shorts per B buffer
  constexpr int LDSL = PL * (ISSA + ISSB); // gload16 issued per wave per stage

  const int z = blockIdx.z;
  int Mt = M;
  int rowbase = 0;
  const int* tl = nullptr;
  if (AMODE != 0) {
    Mt = counts[z];
    if ((int)blockIdx.x * BM >= Mt) return;
    if (AMODE == 1) tl = tokList + offsets[z];
    else rowbase = offsets[z];
  }

  const short* A = Ab + (long)z * sA;
  const short* Al = SPLIT ? (Abl + (long)z * sA) : nullptr;
  const short* B = Bb + (long)z * sB;
  const short* Bl = SPLIT ? (Bbl + (long)z * sB) : nullptr;
  const int tid = threadIdx.x;
  const int lane = tid & 63;
  const int w = tid >> 6;
  const int wrow = w % WROWS;
  const int wcol = w / WROWS;
  const int m0 = blockIdx.x * BM;
  const int n0 = blockIdx.y * BN;

  __shared__ __align__(16) short As[2 * ABUF];
  __shared__ __align__(16) short Bs[2 * BBUF];

  // staging descriptors: lane covers row (lane>>2) of its 16-row segment,
  // source chunk swizzled so frag reads are conflict-free
  const int l4 = lane >> 2;                               // row in segment
  const int lc = (lane & 3) ^ (l4 & 3) ^ ((lane >> 4) & 3); // source 16B chunk
  long agp[ISSA]; int albase[ISSA];
#pragma unroll
  for (int r = 0; r < ISSA; ++r) {
    int seg = w * ISSA + r;
    int row = seg * 16 + l4;
    int grow;
    if (AMODE == 0) grow = m0 + row;
    else if (AMODE == 1) grow = tl[min(m0 + row, Mt - 1)];
    else grow = rowbase + min(m0 + row, Mt - 1);
    agp[r] = (long)grow * lda + lc * 8;
    albase[r] = seg * 512;
  }
  long bgp[ISSB]; int blbase[ISSB];
#pragma unroll
  for (int r = 0; r < ISSB; ++r) {
    int seg = w * ISSB + r;
    int row = seg * 16 + l4;
    bgp[r] = (long)(n0 + row) * ldb + lc * 8;
    blbase[r] = seg * 512;
  }

  floatx4 acc[MT][NT];
#pragma unroll
  for (int i = 0; i < MT; ++i)
#pragma unroll
    for (int j = 0; j < NT; ++j) acc[i][j] = floatx4{0.f, 0.f, 0.f, 0.f};

  // fragment read offsets (swizzle constant per thread: rows step by 16)
  const int am = wrow * WTM + (lane & 15);
  const int bn = wcol * WTN + (lane & 15);
  const int ac = lane >> 4;
  const int aro = am * 32 + ((ac ^ (am & 3) ^ ((am >> 2) & 3)) << 3);
  const int bro = bn * 32 + ((ac ^ (bn & 3) ^ ((bn >> 2) & 3)) << 3);

  // issue all async global->LDS loads for k-tile k0 into buffer `buf`
  auto stage = [&](int buf, int k0) {
    short* Ad = &As[buf * ABUF];
    short* Bd = &Bs[buf * BBUF];
#pragma unroll
    for (int r = 0; r < ISSA; ++r) gload16(A + agp[r] + k0, Ad + albase[r]);
#pragma unroll
    for (int r = 0; r < ISSB; ++r) gload16(B + bgp[r] + k0, Bd + blbase[r]);
    if (SPLIT) {
#pragma unroll
      for (int r = 0; r < ISSA; ++r) gload16(Al + agp[r] + k0, Ad + BM * 32 + albase[r]);
#pragma unroll
      for (int r = 0; r < ISSB; ++r) gload16(Bl + bgp[r] + k0, Bd + BN * 32 + blbase[r]);
    }
  };

  // read frags from buffer `buf` and accumulate MFMAs
  auto compute = [&](int buf) {
    const short* Ar = &As[buf * ABUF];
    const short* Br = &Bs[buf * BBUF];
    short8 afh[MT], bfh[NT];
#pragma unroll
    for (int i = 0; i < MT; ++i) afh[i] = *(const short8*)&Ar[aro + i * 512];
#pragma unroll
    for (int j = 0; j < NT; ++j) bfh[j] = *(const short8*)&Br[bro + j * 512];
    if (SPLIT) {
      short8 afl[MT], bfl[NT];
#pragma unroll
      for (int i = 0; i < MT; ++i) afl[i] = *(const short8*)&Ar[BM * 32 + aro + i * 512];
#pragma unroll
      for (int j = 0; j < NT; ++j) bfl[j] = *(const short8*)&Br[BN * 32 + bro + j * 512];
#pragma unroll
      for (int i = 0; i < MT; ++i)
#pragma unroll
        for (int j = 0; j < NT; ++j) {
          acc[i][j] = __builtin_amdgcn_mfma_f32_16x16x32_bf16(afh[i], bfh[j], acc[i][j], 0, 0, 0);
          acc[i][j] = __builtin_amdgcn_mfma_f32_16x16x32_bf16(afh[i], bfl[j], acc[i][j], 0, 0, 0);
          acc[i][j] = __builtin_amdgcn_mfma_f32_16x16x32_bf16(afl[i], bfh[j], acc[i][j], 0, 0, 0);
        }
    } else {
#pragma unroll
      for (int i = 0; i < MT; ++i)
#pragma unroll
        for (int j = 0; j < NT; ++j)
          acc[i][j] = __builtin_amdgcn_mfma_f32_16x16x32_bf16(afh[i], bfh[j], acc[i][j], 0, 0, 0);
    }
  };

  const int ntile = K >> 5;           // k-steps of 32; every call site has >=2
  // prologue: two tiles in flight, no drain
  stage(0, 0);
  stage(1, 32);
  int cur = 0;
  for (int t = 0; t < ntile - 2; ++t) {
    wait_vmcnt<LDSL>();               // own tile-t loads done; t+1 in flight
    __builtin_amdgcn_s_barrier();     // => every wave's tile-t loads landed
    __builtin_amdgcn_sched_barrier(0);
    compute(cur);                     // no vmem waits inside
    __builtin_amdgcn_sched_barrier(0);
    __builtin_amdgcn_s_barrier();     // => all waves done reading buf cur
    __builtin_amdgcn_sched_barrier(0);
    stage(cur, (t + 2) << 5);         // overwrite buf cur with tile t+2
    cur ^= 1;
  }
  // tile ntile-2: tile ntile-1 stays in flight
  wait_vmcnt<LDSL>();
  __builtin_amdgcn_s_barrier();
  __builtin_amdgcn_sched_barrier(0);
  compute(cur);
  cur ^= 1;
  // tile ntile-1: final drain
  wait_vmcnt<0>();
  __builtin_amdgcn_s_barrier();
  __builtin_amdgcn_sched_barrier(0);
  compute(cur);

  // epilogue: C layout col=lane&15, row=(lane>>4)*4+q
  const float* bz = bias ? (bias + (long)z * sBias) : nullptr;
#pragma unroll
  for (int i = 0; i < MT; ++i) {
    int rt = wrow * WTM + i * 16 + ((lane >> 4) << 2);
#pragma unroll
    for (int j = 0; j < NT; ++j) {
      int col = n0 + wcol * WTN + j * 16 + (lane & 15);
      float badd = bz ? bz[col] : 0.f;
      floatx4 v = acc[i][j];
#pragma unroll
      for (int q = 0; q < 4; ++q) {
        int r = m0 + rt + q;
        if (AMODE != 0 && r >= Mt) break;
        long orow = (AMODE == 1) ? ((long)offsets[z] + r)
                  : (AMODE == 2) ? ((long)rowbase + r) : (long)r;
        float val = v[q] * scale + badd;
        if (RELU) val = fmaxf(val, 0.f);
        if (EPI == 0) {
          ((short*)Cb)[(long)z * sC + orow * ldc + col] = f2bf(val);
        } else {
          float* Cf = (float*)Cb + (long)z * sC;
          if (srcadd) val += srcadd[orow * ldc + col];
          Cf[orow * ldc + col] = val;
        }
      }
    }
  }
}

// f32 -> hi/lo bf16 planes
__global__ void split_bf16(const float* __restrict__ src, short* __restrict__ hi,
                           short* __restrict__ lo, int n) {
  int i = (blockIdx.x * 256 + threadIdx.x) * 4;
  if (i >= n) return;
  float4 v = *(const float4*)(src + i);
  short h0 = f2bf(v.x), h1 = f2bf(v.y), h2 = f2bf(v.z), h3 = f2bf(v.w);
  short4v oh = { h0, h1, h2, h3 };
  short4v ol = { f2bf(v.x - bf2f(h0)), f2bf(v.y - bf2f(h1)),
                 f2bf(v.z - bf2f(h2)), f2bf(v.w - bf2f(h3)) };
  *(short4v*)(hi + i) = oh;
  *(short4v*)(lo + i) = ol;
}

// f32 [R,C] -> bf16 [C,R] per batch z (R,C multiples of 64)
__global__ void transpose_bf16(const float* __restrict__ src, short* __restrict__ dst,
                               int R, int C) {
  __shared__ float t[64][65];
  long zoff = (long)blockIdx.z * R * C;
  const float* s = src + zoff;
  short* d = dst + zoff;
  int r0 = blockIdx.y * 64, c0 = blockIdx.x * 64;
  int tid = threadIdx.x;
#pragma unroll
  for (int i = 0; i < 16; ++i) {
    int flat = i * 256 + tid;
    int r = flat >> 6, c = flat & 63;
    t[r][c] = s[(long)(r0 + r) * C + c0 + c];
  }
  __syncthreads();
#pragma unroll
  for (int i = 0; i < 16; ++i) {
    int flat = i * 256 + tid;
    int c = flat >> 6, r = flat & 63;
    d[(long)(c0 + c) * R + r0 + r] = f2bf(t[r][c]);
  }
}

// qkv f32 [T,3072] -> Q,K hi/lo [pair][S][dh], Vt hi/lo [pair][dh][S]
__global__ void repack_qkv_split(const float* __restrict__ qkv,
                                 short* __restrict__ Qh, short* __restrict__ Ql,
                                 short* __restrict__ Kh, short* __restrict__ Kl,
                                 short* __restrict__ Vh, short* __restrict__ Vl) {
  long idx = (long)blockIdx.x * 256 + threadIdx.x;
  int t = (int)(idx / 3072), c = (int)(idx % 3072);
  int sec = c >> 10, within = c & 1023;
  int h = within >> 6, di = within & 63;
  int b = t >> 10, s = t & 1023;
  int g = b * NHEADS + h;
  float v = qkv[idx];
  short vh = f2bf(v);
  short vl = f2bf(v - bf2f(vh));
  if (sec == 2) {
    long vo = (long)g * 65536 + di * 1024 + s;
    Vh[vo] = vh; Vl[vo] = vl;
  } else {
    long qo = (long)g * 65536 + s * 64 + di;
    if (sec == 0) { Qh[qo] = vh; Ql[qo] = vl; }
    else          { Kh[qo] = vh; Kl[qo] = vl; }
  }
}

// row softmax on f32, write P as hi plane [0,1024) + lo plane [1024,2048) shorts
__global__ void softmax_rows_split(float* __restrict__ scores) {
  __shared__ float wred[4], wsum[4];
  long row = blockIdx.x;
  float* p = scores + row * 1024;
  int tid = threadIdx.x;
  float4 v = *(const float4*)(p + tid * 4);
  float mx = fmaxf(fmaxf(v.x, v.y), fmaxf(v.z, v.w));
  for (int m = 1; m < 64; m <<= 1) mx = fmaxf(mx, __shfl_xor(mx, m));
  if ((tid & 63) == 0) wred[tid >> 6] = mx;
  __syncthreads();
  mx = fmaxf(fmaxf(wred[0], wred[1]), fmaxf(wred[2], wred[3]));
  float e0 = expf(v.x - mx), e1 = expf(v.y - mx), e2 = expf(v.z - mx), e3 = expf(v.w - mx);
  float sm = e0 + e1 + e2 + e3;
  for (int m = 1; m < 64; m <<= 1) sm += __shfl_xor(sm, m);
  if ((tid & 63) == 0) wsum[tid >> 6] = sm;
  __syncthreads();
  float inv = 1.f / (wsum[0] + wsum[1] + wsum[2] + wsum[3]);
  float y0 = e0 * inv, y1 = e1 * inv, y2 = e2 * inv, y3 = e3 * inv;
  short h0 = f2bf(y0), h1 = f2bf(y1), h2 = f2bf(y2), h3 = f2bf(y3);
  short4v oh = { h0, h1, h2, h3 };
  short4v ol = { f2bf(y0 - bf2f(h0)), f2bf(y1 - bf2f(h1)),
                 f2bf(y2 - bf2f(h2)), f2bf(y3 - bf2f(h3)) };
  short* ps = (short*)p;
  *(short4v*)(ps + tid * 4) = oh;
  *(short4v*)(ps + 1024 + tid * 4) = ol;
}

// layer norm over rows of 1024; optional f32 and bf16 outputs
__global__ void ln_rows(const float* __restrict__ x, const float* __restrict__ g,
                        const float* __restrict__ b, float* __restrict__ of,
                        short* __restrict__ ob) {
  __shared__ float ws1[4], ws2[4];
  long row = blockIdx.x;
  const float* p = x + row * 1024;
  int tid = threadIdx.x;
  float4 v = *(const float4*)(p + tid * 4);
  float s = v.x + v.y + v.z + v.w;
  float s2 = v.x * v.x + v.y * v.y + v.z * v.z + v.w * v.w;
  for (int m = 1; m < 64; m <<= 1) { s += __shfl_xor(s, m); s2 += __shfl_xor(s2, m); }
  if ((tid & 63) == 0) { ws1[tid >> 6] = s; ws2[tid >> 6] = s2; }
  __syncthreads();
  s = ws1[0] + ws1[1] + ws1[2] + ws1[3];
  s2 = ws2[0] + ws2[1] + ws2[2] + ws2[3];
  float mean = s * (1.f / 1024.f);
  float var = s2 * (1.f / 1024.f) - mean * mean;
  float rstd = rsqrtf(var + 1e-5f);
  float4 gg = *(const float4*)(g + tid * 4);
  float4 bb = *(const float4*)(b + tid * 4);
  float y0 = (v.x - mean) * rstd * gg.x + bb.x;
  float y1 = (v.y - mean) * rstd * gg.y + bb.y;
  float y2 = (v.z - mean) * rstd * gg.z + bb.z;
  float y3 = (v.w - mean) * rstd * gg.w + bb.w;
  if (of) { float4 o = { y0, y1, y2, y3 }; *(float4*)(of + row * 1024 + tid * 4) = o; }
  if (ob) { short4v o = { f2bf(y0), f2bf(y1), f2bf(y2), f2bf(y3) }; *(short4v*)(ob + row * 1024 + tid * 4) = o; }
}

// moe combine + LN2: out = LN(accum + g1*y[pos1] + g2*y[pos2])
__global__ void combine_ln2(const float* __restrict__ accum, const float* __restrict__ y,
                            const int* __restrict__ pos1, const int* __restrict__ pos2,
                            const float* __restrict__ g1a, const float* __restrict__ g2a,
                            const float* __restrict__ gn, const float* __restrict__ bn,
                            float* __restrict__ out) {
  __shared__ float ws1[4], ws2[4];
  int t = blockIdx.x;
  int tid = threadIdx.x;
  const float* a = accum + (long)t * 1024;
  const float* y1 = y + (long)pos1[t] * 1024;
  const float* y2 = y + (long)pos2[t] * 1024;
  float G1 = g1a[t], G2 = g2a[t];
  float4 va = *(const float4*)(a + tid * 4);
  float4 v1 = *(const float4*)(y1 + tid * 4);
  float4 v2 = *(const float4*)(y2 + tid * 4);
  float x0 = va.x + G1 * v1.x + G2 * v2.x;
  float x1 = va.y + G1 * v1.y + G2 * v2.y;
  float x2 = va.z + G1 * v1.z + G2 * v2.z;
  float x3 = va.w + G1 * v1.w + G2 * v2.w;
  float s = x0 + x1 + x2 + x3;
  float s2 = x0 * x0 + x1 * x1 + x2 * x2 + x3 * x3;
  for (int m = 1; m < 64; m <<= 1) { s += __shfl_xor(s, m); s2 += __shfl_xor(s2, m); }
  if ((tid & 63) == 0) { ws1[tid >> 6] = s; ws2[tid >> 6] = s2; }
  __syncthreads();
  s = ws1[0] + ws1[1] + ws1[2] + ws1[3];
  s2 = ws2[0] + ws2[1] + ws2[2] + ws2[3];
  float mean = s * (1.f / 1024.f);
  float var = s2 * (1.f / 1024.f) - mean * mean;
  float rstd = rsqrtf(var + 1e-5f);
  float4 gg = *(const float4*)(gn + tid * 4);
  float4 bb = *(const float4*)(bn + tid * 4);
  float4 o = { (x0 - mean) * rstd * gg.x + bb.x,
               (x1 - mean) * rstd * gg.y + bb.y,
               (x2 - mean) * rstd * gg.z + bb.z,
               (x3 - mean) * rstd * gg.w + bb.w };
  *(float4*)(out + (long)t * 1024 + tid * 4) = o;
}

// router pass 1: one wave per token; NO global atomics.
__global__ void router_compute(const float* __restrict__ x, const float* __restrict__ rw,
                               const float* __restrict__ rb,
                               int* __restrict__ top1, int* __restrict__ top2,
                               float* __restrict__ g1o, float* __restrict__ g2o,
                               float* __restrict__ partialP) {
  __shared__ float pp[4][8];
  int w = threadIdx.x >> 6, lane = threadIdx.x & 63;
  int t = blockIdx.x * 4 + w;
  const float* xp = x + (long)t * 1024;
  float xv[16];
#pragma unroll
  for (int i = 0; i < 16; ++i) xv[i] = xp[lane + i * 64];
  float logit[8];
#pragma unroll
  for (int e = 0; e < 8; ++e) {
    const float* wp = rw + e * 1024;
    double a = 0.0;
#pragma unroll
    for (int i = 0; i < 16; ++i) a += (double)xv[i] * (double)wp[lane + i * 64];
    for (int m = 1; m < 64; m <<= 1) a += __shfl_xor(a, m);
    logit[e] = (float)a + rb[e];
  }
  float mx = logit[0];
#pragma unroll
  for (int e = 1; e < 8; ++e) mx = fmaxf(mx, logit[e]);
  float pe[8], sum = 0.f;
#pragma unroll
  for (int e = 0; e < 8; ++e) { pe[e] = expf(logit[e] - mx); sum += pe[e]; }
  float inv = 1.f / sum;
#pragma unroll
  for (int e = 0; e < 8; ++e) pe[e] *= inv;
  int i1 = 0;
#pragma unroll
  for (int e = 1; e < 8; ++e) if (pe[e] > pe[i1]) i1 = e;
  int i2 = (i1 == 0) ? 1 : 0;
#pragma unroll
  for (int e = 0; e < 8; ++e) if (e != i1 && pe[e] > pe[i2]) i2 = e;
  float denom = pe[i1] + pe[i2];
  if (lane == 0) {
    top1[t] = i1; top2[t] = i2;
    g1o[t] = pe[i1] / denom; g2o[t] = pe[i2] / denom;
#pragma unroll
    for (int e = 0; e < 8; ++e) pp[w][e] = pe[e];
  }
  __syncthreads();
  if (threadIdx.x < 8) {
    partialP[(long)blockIdx.x * 8 + threadIdx.x] =
        pp[0][threadIdx.x] + pp[1][threadIdx.x] + pp[2][threadIdx.x] + pp[3][threadIdx.x];
  }
}

// router pass 2 (ONE block, 1024 threads): probsum reduce, counting-sort
// tokens into packed per-expert lists (contention-free), lb loss.
__global__ void __launch_bounds__(1024) router_finalize(
    const float* __restrict__ partialP,
    const int* __restrict__ top1, const int* __restrict__ top2,
    int* __restrict__ counts, int* __restrict__ eoff_out,
    int* __restrict__ tokList, int* __restrict__ pos1, int* __restrict__ pos2,
    float* __restrict__ lb_out) {
  __shared__ float redP[16][8];
  __shared__ int wtot[16][8];
  __shared__ int tot[8], eoff[8];
  __shared__ float psum[8];
  int tid = threadIdx.x;
  int lane = tid & 63, wv = tid >> 6;

  float p[8];
#pragma unroll
  for (int e = 0; e < 8; ++e) p[e] = partialP[(long)tid * 8 + e];
  for (int m = 1; m < 64; m <<= 1)
#pragma unroll
    for (int e = 0; e < 8; ++e) p[e] += __shfl_xor(p[e], m);
  if (lane == 0)
#pragma unroll
    for (int e = 0; e < 8; ++e) redP[wv][e] = p[e];

  int c[8] = {0, 0, 0, 0, 0, 0, 0, 0};
  int expid[8];
#pragma unroll
  for (int j = 0; j < 8; ++j) {
    int i = tid * 8 + j;
    int t = i >> 1;
    int e = (i & 1) ? top2[t] : top1[t];
    expid[j] = e;
    c[e]++;
  }
  int inc[8];
#pragma unroll
  for (int e = 0; e < 8; ++e) inc[e] = c[e];
  for (int d = 1; d < 64; d <<= 1) {
#pragma unroll
    for (int e = 0; e < 8; ++e) {
      int o = __shfl_up(inc[e], d);
      if (lane >= d) inc[e] += o;
    }
  }
  if (lane == 63)
#pragma unroll
    for (int e = 0; e < 8; ++e) wtot[wv][e] = inc[e];
  __syncthreads();
  if (tid < 8) {
    int run = 0;
#pragma unroll
    for (int w = 0; w < 16; ++w) { int v = wtot[w][tid]; wtot[w][tid] = run; run += v; }
    tot[tid] = run;
    float s = 0.f;
#pragma unroll
    for (int w = 0; w < 16; ++w) s += redP[w][tid];
    psum[tid] = s;
  }
  __syncthreads();
  if (tid == 0) {
    int off = 0;
#pragma unroll
    for (int e = 0; e < 8; ++e) { eoff[e] = off; off += tot[e]; }
  }
  __syncthreads();
  int base[8], c2[8] = {0, 0, 0, 0, 0, 0, 0, 0};
#pragma unroll
  for (int e = 0; e < 8; ++e) base[e] = eoff[e] + wtot[wv][e] + inc[e] - c[e];
#pragma unroll
  for (int j = 0; j < 8; ++j) {
    int i = tid * 8 + j;
    int t = i >> 1;
    int e = expid[j];
    int dest = base[e] + c2[e]++;
    tokList[dest] = t;
    if (i & 1) pos2[t] = dest; else pos1[t] = dest;
  }
  if (tid < 8) { counts[tid] = tot[tid]; eoff_out[tid] = eoff[tid]; }
  if (tid == 0) {
    float lb = 0.f;
#pragma unroll
    for (int e = 0; e < 8; ++e)
      lb += ((float)tot[e] / 8192.f) * (psum[e] / 4096.f);
    *lb_out = 8.f * lb;
  }
}

__global__ void sentinel_kernel(float* out, int n) {
  if (threadIdx.x == 0) { out[0] = 1e9f; out[n - 1] = 1e9f; }
}

// ---------------------------------------------------------------------------
extern "C" void kernel_launch(void* const* d_in, const int* in_sizes, int n_in,
                              void* d_out, int out_size, void* d_ws, size_t ws_size,
                              hipStream_t stream) {
  const float* src        = (const float*)d_in[0];
  const float* in_proj_w  = (const float*)d_in[1];
  const float* in_proj_b  = (const float*)d_in[2];
  const float* out_proj_w = (const float*)d_in[3];
  const float* out_proj_b = (const float*)d_in[4];
  const float* ln1_g      = (const float*)d_in[5];
  const float* ln1_b      = (const float*)d_in[6];
  const float* router_w   = (const float*)d_in[7];
  const float* router_b   = (const float*)d_in[8];
  const float* w1         = (const float*)d_in[9];
  const float* b1         = (const float*)d_in[10];
  const float* w2         = (const float*)d_in[11];
  const float* b2         = (const float*)d_in[12];
  const float* ln2_g      = (const float*)d_in[13];
  const float* ln2_b      = (const float*)d_in[14];
  float* out = (float*)d_out;

  char* ws = (char*)d_ws;
  size_t off = 0;
  auto alloc = [&](size_t bytes) -> char* {
    char* p = ws + off;
    off += (bytes + 255) & ~(size_t)255;
    return p;
  };
  // big block: Q/K/V hi+lo planes during attention; w1t/w2t after
  char*  blockW = alloc(8ll * (DFF * DMODEL + DMODEL * DFF) * 2);  // 128MB
  short* Qh = (short*)(blockW + 0ll  * 1024 * 1024);
  short* Ql = (short*)(blockW + 8ll  * 1024 * 1024);
  short* Kh = (short*)(blockW + 16ll * 1024 * 1024);
  short* Kl = (short*)(blockW + 24ll * 1024 * 1024);
  short* Vh = (short*)(blockW + 32ll * 1024 * 1024);
  short* Vl = (short*)(blockW + 40ll * 1024 * 1024);
  short* w1t = (short*)blockW;                                      // [E][dff][d]
  short* w2t = (short*)(blockW + 8ll * DFF * DMODEL * 2);           // [E][d][dff]
  short* winh  = (short*)alloc(3072ll * 1024 * 2);
  short* winl  = (short*)alloc(3072ll * 1024 * 2);
  short* wouth = (short*)alloc(1024ll * 1024 * 2);
  short* woutl = (short*)alloc(1024ll * 1024 * 2);
  short* xh    = (short*)alloc((long)TOKENS * DMODEL * 2);
  short* xl    = (short*)alloc((long)TOKENS * DMODEL * 2);
  char*  reg1  = alloc((long)TOKENS * 3072 * 4);     // 48MB: qkv f32 -> O planes/x1 -> y
  float* qkvf  = (float*)reg1;
  float* Of32  = (float*)reg1;
  short* Ohi   = (short*)(reg1 + 16ll * 1024 * 1024);
  short* Olo   = (short*)(reg1 + 24ll * 1024 * 1024);
  float* x1    = (float*)(reg1 + 32ll * 1024 * 1024);
  float* y     = (float*)reg1;                       // packed expert outputs [8192,1024] f32
  char*  reg2  = alloc(16ll * 1024 * 1024 * 4);      // 64MB: scores chunk -> h
  float* scores = (float*)reg2;
  short* h      = (short*)reg2;
  short* x1nbf = (short*)alloc((long)TOKENS * DMODEL * 2);
  float* accum = (float*)alloc((long)TOKENS * DMODEL * 4);
  float* partialP = (float*)alloc(1024 * 8 * 4);
  int*   top1   = (int*)alloc(TOKENS * 4);
  int*   top2   = (int*)alloc(TOKENS * 4);
  float* g1a    = (float*)alloc(TOKENS * 4);
  float* g2a    = (float*)alloc(TOKENS * 4);
  int*   pos1   = (int*)alloc(TOKENS * 4);
  int*   pos2   = (int*)alloc(TOKENS * 4);
  int*   counts = (int*)alloc(32);
  int*   eoff   = (int*)alloc(32);
  int*   tokList = (int*)alloc(2 * TOKENS * 4);
  size_t needed = off;

  if (ws_size < needed) {
    sentinel_kernel<<<1, 64, 0, stream>>>(out, out_size);
    return;
  }

  // splits of f32 inputs
  split_bf16<<<3072 * 1024 / 1024, 256, 0, stream>>>(in_proj_w, winh, winl, 3072 * 1024);
  split_bf16<<<1024 * 1024 / 1024, 256, 0, stream>>>(out_proj_w, wouth, woutl, 1024 * 1024);
  split_bf16<<<TOKENS * DMODEL / 1024, 256, 0, stream>>>(src, xh, xl, TOKENS * DMODEL);

  // QKV projection (split): qkv f32 = x @ win^T + b
  gemm_nt<128, 128, 64, 64, 1, 0, false, true><<<dim3(32, 24, 1), 256, 0, stream>>>(
      xh, xl, 1024, 0, winh, winl, 1024, 0, qkvf, 3072, 0,
      TOKENS, 3072, 1024, 1.f, in_proj_b, 0, nullptr, nullptr, nullptr, nullptr);
  repack_qkv_split<<<(int)((long)TOKENS * 3072 / 256), 256, 0, stream>>>(qkvf, Qh, Ql, Kh, Kl, Vh, Vl);

  // attention, chunked by batch (16 pairs per chunk)
  for (int c = 0; c < 4; ++c) {
    long co = (long)c * 16 * 65536;
    gemm_nt<128, 128, 64, 64, 1, 0, false, true><<<dim3(8, 8, 16), 256, 0, stream>>>(
        Qh + co, Ql + co, 64, 65536, Kh + co, Kl + co, 64, 65536, scores, 1024, 1048576,
        1024, 1024, 64, 0.125f, nullptr, 0, nullptr, nullptr, nullptr, nullptr);
    softmax_rows_split<<<16 * 1024, 256, 0, stream>>>(scores);
    // P(hi/lo in place, pitch 2048 shorts) @ V^T -> O f32
    gemm_nt<128, 64, 64, 32, 1, 0, false, true><<<dim3(8, 1, 16), 256, 0, stream>>>(
        (const short*)scores, (const short*)scores + 1024, 2048, 2097152,
        Vh + co, Vl + co, 1024, 65536,
        Of32 + (long)c * 1048576, 1024, 64,
        1024, 64, 1024, 1.f, nullptr, 0, nullptr, nullptr, nullptr, nullptr);
  }

  // expert weight transposes now (blockW's Q/K/V no longer needed)
  transpose_bf16<<<dim3(DFF / 64, DMODEL / 64, 8), 256, 0, stream>>>(w1, w1t, DMODEL, DFF);
  transpose_bf16<<<dim3(DMODEL / 64, DFF / 64, 8), 256, 0, stream>>>(w2, w2t, DFF, DMODEL);

  // split O, then out-projection (split) + bias + residual(src) -> x1 f32
  split_bf16<<<TOKENS * DMODEL / 1024, 256, 0, stream>>>(Of32, Ohi, Olo, TOKENS * DMODEL);
  gemm_nt<128, 128, 64, 64, 1, 0, false, true><<<dim3(32, 8, 1), 256, 0, stream>>>(
      Ohi, Olo, 1024, 0, wouth, woutl, 1024, 0, x1, 1024, 0,
      TOKENS, 1024, 1024, 1.f, out_proj_b, 0, src, nullptr, nullptr, nullptr);

  // LN1 -> accum (f32 residual base) + x1nbf (bf16 expert input)
  ln_rows<<<TOKENS, 256, 0, stream>>>(x1, ln1_g, ln1_b, accum, x1nbf);

  // router (atomic-free)
  router_compute<<<TOKENS / 4, 256, 0, stream>>>(accum, router_w, router_b,
                                                 top1, top2, g1a, g2a, partialP);
  router_finalize<<<1, 1024, 0, stream>>>(partialP, top1, top2, counts, eoff,
                                          tokList, pos1, pos2, out + (out_size - 1));

  // expert GEMM1: h = relu(gather(x1nbf) @ w1t[e]^T + b1[e]) (packed bf16)
  gemm_nt<128, 128, 64, 64, 0, 1, true, false><<<dim3(32, 32, 8), 256, 0, stream>>>(
      x1nbf, nullptr, 1024, 0, w1t, nullptr, 1024, (long)DFF * DMODEL, h, DFF, 0,
      0, DFF, 1024, 1.f, b1, DFF, nullptr, tokList, counts, eoff);

  // expert GEMM2: y[packed] = h @ w2t[e]^T + b2[e]  (f32 store, no atomics)
  gemm_nt<128, 128, 64, 64, 1, 2, false, false><<<dim3(32, 8, 8), 256, 0, stream>>>(
      h, nullptr, DFF, 0, w2t, nullptr, DFF, (long)DMODEL * DFF, y, 1024, 0,
      0, DMODEL, DFF, 1.f, b2, DMODEL, nullptr, tokList, counts, eoff);

  // combine + LN2 -> final output
  combine_ln2<<<TOKENS, 256, 0, stream>>>(accum, y, pos1, pos2, g1a, g2a,
                                          ln2_g, ln2_b, out);
}

// Round 4
// 1163.894 us; speedup vs baseline: 1.4154x; 1.3250x over previous
//
#include <hip/hip_runtime.h>

// ---------------------------------------------------------------------------
// TransformerEncoderLayerWithMoE on MI355X (gfx950)
// Round 8: XCD-locality work remap. R0-R3 showed GEMM1/2 pinned at
// ~1 TB/s effective memory throughput regardless of k-loop schedule
// (dur ~= hbm_bytes / 1TB/s every round). Overfetch is 3.3x: blocks
// sharing operand panels land on different XCDs (round-robin dispatch),
// so each per-XCD L2 refetches its own copy. Fix: 8 experts = 8 XCDs.
//   AMODE!=0: expert e -> all blocks at dispatch positions == e (mod 8)
//             (one expert per XCD; A-expert ~2MB stays L2-resident;
//              GEMM2 reads h on the same XCD that GEMM1 wrote it).
//   AMODE==0: chunked swizzle (cpx = nwg/8) so consecutive-x blocks
//             sharing a B panel are co-resident on one XCD.
// K-loop reverted to the best-measured R1 schedule (compute -> stage ->
// __syncthreads, double-buffered).
// ---------------------------------------------------------------------------

typedef __attribute__((ext_vector_type(8))) short short8;   // 8 bf16 = 4 VGPRs
typedef __attribute__((ext_vector_type(4))) short short4v;
typedef __attribute__((ext_vector_type(4))) float floatx4;  // MFMA C/D frag

#define TOKENS 4096
#define DMODEL 1024
#define NHEADS 16
#define DHEAD  64
#define DFF    4096
#define NEXP   8
#define SEQ    1024
#define NPAIR  64   // BATCH*NHEADS

// RNE float->bf16 (finite inputs only)
__device__ inline short f2bf(float f) {
  unsigned u = __builtin_bit_cast(unsigned, f);
  unsigned r = (u + 0x7fffu + ((u >> 16) & 1u)) >> 16;
  return (short)r;
}
__device__ inline float bf2f(short h) {
  return __builtin_bit_cast(float, ((unsigned)(unsigned short)h) << 16);
}

// async 16B/lane global->LDS DMA; lds dest = wave-uniform base + lane*16
__device__ inline void gload16(const short* g, short* l) {
  __builtin_amdgcn_global_load_lds(
      (const __attribute__((address_space(1))) unsigned int*)g,
      (__attribute__((address_space(3))) unsigned int*)l, 16, 0, 0);
}

// ---------------------------------------------------------------------------
// NT GEMM: C[m,n] = scale * sum_k A[m,k]*B[n,k] (+bias[n]) (+src)
// SPLIT: A/B given as hi+lo bf16 planes; acc += Ah*Bh + Ah*Bl + Al*Bh
// EPI: 0 = bf16 store, 1 = f32 store (+optional srcadd)
// AMODE: 0 = linear rows, 1 = gathered rows via packed tokList, 2 = offset rows
// LDS layout: unpadded [rows][32] shorts, 16B chunk c of row r stored at
// chunk position c ^ (r&3) ^ ((r>>2)&3)  (bank-conflict-free, DMA-compatible)
// Double-buffered R1 schedule: compute(t); stage(t+1); __syncthreads().
// ---------------------------------------------------------------------------
template<int BM, int BN, int WTM, int WTN, int EPI, int AMODE, bool RELU, bool SPLIT>
__global__ void __launch_bounds__((BM / WTM) * (BN / WTN) * 64)
gemm_nt(const short* __restrict__ Ab, const short* __restrict__ Abl, int lda, long sA,
        const short* __restrict__ Bb, const short* __restrict__ Bbl, int ldb, long sB,
        void* __restrict__ Cb, int ldc, long sC,
        int M, int N, int K, float scale,
        const float* __restrict__ bias, int sBias,
        const float* __restrict__ srcadd,
        const int* __restrict__ tokList,
        const int* __restrict__ counts,
        const int* __restrict__ offsets)
{
  constexpr int WROWS = BM / WTM;
  constexpr int WCOLS = BN / WTN;
  constexpr int NW = WROWS * WCOLS;
  constexpr int MT = WTM / 16;
  constexpr int NT = WTN / 16;
  constexpr int ISSA = (BM / 16) / NW;   // 1024B (16 rows) per wave-issue
  constexpr int ISSB = (BN / 16) / NW;
  constexpr int PL = SPLIT ? 2 : 1;
  constexpr int ABUF = PL * BM * 32;     // shorts per A buffer
  constexpr int BBUF = PL * BN * 32;     // shorts per B buffer

  // --- XCD-locality work remap (dispatch position % 8 ~ XCD) ---
  int xw, yw, zw;
  if (AMODE != 0) {
    // expert GEMMs (gridDim.z == NEXP == 8): one expert per XCD.
    int flat = blockIdx.x + gridDim.x * (blockIdx.y + gridDim.y * blockIdx.z);
    zw = flat & 7;                       // expert = XCD residue
    int m = flat >> 3;                   // bijective: covers gx*gy per expert
    xw = m % gridDim.x;
    yw = m / gridDim.x;
  } else {
    // dense GEMMs: contiguous chunk per XCD within each z (nwg % 8 == 0
    // at every call site), so consecutive-x blocks sharing a B panel are
    // co-resident on one XCD's L2.
    int nwg = gridDim.x * gridDim.y;
    int f2 = blockIdx.x + gridDim.x * blockIdx.y;
    int cpx = nwg >> 3;
    int g = (f2 & 7) * cpx + (f2 >> 3);
    xw = g % gridDim.x;
    yw = g / gridDim.x;
    zw = blockIdx.z;
  }

  const int z = zw;
  int Mt = M;
  int rowbase = 0;
  const int* tl = nullptr;
  if (AMODE != 0) {
    Mt = counts[z];
    if (xw * BM >= Mt) return;
    if (AMODE == 1) tl = tokList + offsets[z];
    else rowbase = offsets[z];
  }

  const short* A = Ab + (long)z * sA;
  const short* Al = SPLIT ? (Abl + (long)z * sA) : nullptr;
  const short* B = Bb + (long)z * sB;
  const short* Bl = SPLIT ? (Bbl + (long)z * sB) : nullptr;
  const int tid = threadIdx.x;
  const int lane = tid & 63;
  const int w = tid >> 6;
  const int wrow = w % WROWS;
  const int wcol = w / WROWS;
  const int m0 = xw * BM;
  const int n0 = yw * BN;

  __shared__ __align__(16) short As[2 * ABUF];
  __shared__ __align__(16) short Bs[2 * BBUF];

  // staging descriptors: lane covers row (lane>>2) of its 16-row segment,
  // source chunk swizzled so frag reads are conflict-free
  const int l4 = lane >> 2;                               // row in segment
  const int lc = (lane & 3) ^ (l4 & 3) ^ ((lane >> 4) & 3); // source 16B chunk
  long agp[ISSA]; int albase[ISSA];
#pragma unroll
  for (int r = 0; r < ISSA; ++r) {
    int seg = w * ISSA + r;
    int row = seg * 16 + l4;
    int grow;
    if (AMODE == 0) grow = m0 + row;
    else if (AMODE == 1) grow = tl[min(m0 + row, Mt - 1)];
    else grow = rowbase + min(m0 + row, Mt - 1);
    agp[r] = (long)grow * lda + lc * 8;
    albase[r] = seg * 512;
  }
  long bgp[ISSB]; int blbase[ISSB];
#pragma unroll
  for (int r = 0; r < ISSB; ++r) {
    int seg = w * ISSB + r;
    int row = seg * 16 + l4;
    bgp[r] = (long)(n0 + row) * ldb + lc * 8;
    blbase[r] = seg * 512;
  }

  floatx4 acc[MT][NT];
#pragma unroll
  for (int i = 0; i < MT; ++i)
#pragma unroll
    for (int j = 0; j < NT; ++j) acc[i][j] = floatx4{0.f, 0.f, 0.f, 0.f};

  // fragment read offsets (swizzle constant per thread: rows step by 16)
  const int am = wrow * WTM + (lane & 15);
  const int bn = wcol * WTN + (lane & 15);
  const int ac = lane >> 4;
  const int aro = am * 32 + ((ac ^ (am & 3) ^ ((am >> 2) & 3)) << 3);
  const int bro = bn * 32 + ((ac ^ (bn & 3) ^ ((bn >> 2) & 3)) << 3);

  // issue all async global->LDS loads for k-tile k0 into buffer `buf`
  auto stage = [&](int buf, int k0) {
    short* Ad = &As[buf * ABUF];
    short* Bd = &Bs[buf * BBUF];
#pragma unroll
    for (int r = 0; r < ISSA; ++r) gload16(A + agp[r] + k0, Ad + albase[r]);
#pragma unroll
    for (int r = 0; r < ISSB; ++r) gload16(B + bgp[r] + k0, Bd + blbase[r]);
    if (SPLIT) {
#pragma unroll
      for (int r = 0; r < ISSA; ++r) gload16(Al + agp[r] + k0, Ad + BM * 32 + albase[r]);
#pragma unroll
      for (int r = 0; r < ISSB; ++r) gload16(Bl + bgp[r] + k0, Bd + BN * 32 + blbase[r]);
    }
  };

  // read frags from buffer `buf` and accumulate MFMAs
  auto compute = [&](int buf) {
    const short* Ar = &As[buf * ABUF];
    const short* Br = &Bs[buf * BBUF];
    short8 afh[MT], bfh[NT];
#pragma unroll
    for (int i = 0; i < MT; ++i) afh[i] = *(const short8*)&Ar[aro + i * 512];
#pragma unroll
    for (int j = 0; j < NT; ++j) bfh[j] = *(const short8*)&Br[bro + j * 512];
    if (SPLIT) {
      short8 afl[MT], bfl[NT];
#pragma unroll
      for (int i = 0; i < MT; ++i) afl[i] = *(const short8*)&Ar[BM * 32 + aro + i * 512];
#pragma unroll
      for (int j = 0; j < NT; ++j) bfl[j] = *(const short8*)&Br[BN * 32 + bro + j * 512];
#pragma unroll
      for (int i = 0; i < MT; ++i)
#pragma unroll
        for (int j = 0; j < NT; ++j) {
          acc[i][j] = __builtin_amdgcn_mfma_f32_16x16x32_bf16(afh[i], bfh[j], acc[i][j], 0, 0, 0);
          acc[i][j] = __builtin_amdgcn_mfma_f32_16x16x32_bf16(afh[i], bfl[j], acc[i][j], 0, 0, 0);
          acc[i][j] = __builtin_amdgcn_mfma_f32_16x16x32_bf16(afl[i], bfh[j], acc[i][j], 0, 0, 0);
        }
    } else {
#pragma unroll
      for (int i = 0; i < MT; ++i)
#pragma unroll
        for (int j = 0; j < NT; ++j)
          acc[i][j] = __builtin_amdgcn_mfma_f32_16x16x32_bf16(afh[i], bfh[j], acc[i][j], 0, 0, 0);
    }
  };

  const int ntile = K >> 5;           // k-steps of 32
  // R1 schedule (best measured): prologue stage + drain, then
  // compute(t) -> stage(t+1) -> barrier per k-step.
  stage(0, 0);
  __syncthreads();
  int cur = 0;
  for (int t = 0; t < ntile - 1; ++t) {
    compute(cur);
    stage(cur ^ 1, (t + 1) << 5);
    __syncthreads();
    cur ^= 1;
  }
  compute(cur);

  // epilogue: C layout col=lane&15, row=(lane>>4)*4+q
  const float* bz = bias ? (bias + (long)z * sBias) : nullptr;
#pragma unroll
  for (int i = 0; i < MT; ++i) {
    int rt = wrow * WTM + i * 16 + ((lane >> 4) << 2);
#pragma unroll
    for (int j = 0; j < NT; ++j) {
      int col = n0 + wcol * WTN + j * 16 + (lane & 15);
      float badd = bz ? bz[col] : 0.f;
      floatx4 v = acc[i][j];
#pragma unroll
      for (int q = 0; q < 4; ++q) {
        int r = m0 + rt + q;
        if (AMODE != 0 && r >= Mt) break;
        long orow = (AMODE == 1) ? ((long)offsets[z] + r)
                  : (AMODE == 2) ? ((long)rowbase + r) : (long)r;
        float val = v[q] * scale + badd;
        if (RELU) val = fmaxf(val, 0.f);
        if (EPI == 0) {
          ((short*)Cb)[(long)z * sC + orow * ldc + col] = f2bf(val);
        } else {
          float* Cf = (float*)Cb + (long)z * sC;
          if (srcadd) val += srcadd[orow * ldc + col];
          Cf[orow * ldc + col] = val;
        }
      }
    }
  }
}

// f32 -> hi/lo bf16 planes
__global__ void split_bf16(const float* __restrict__ src, short* __restrict__ hi,
                           short* __restrict__ lo, int n) {
  int i = (blockIdx.x * 256 + threadIdx.x) * 4;
  if (i >= n) return;
  float4 v = *(const float4*)(src + i);
  short h0 = f2bf(v.x), h1 = f2bf(v.y), h2 = f2bf(v.z), h3 = f2bf(v.w);
  short4v oh = { h0, h1, h2, h3 };
  short4v ol = { f2bf(v.x - bf2f(h0)), f2bf(v.y - bf2f(h1)),
                 f2bf(v.z - bf2f(h2)), f2bf(v.w - bf2f(h3)) };
  *(short4v*)(hi + i) = oh;
  *(short4v*)(lo + i) = ol;
}

// f32 [R,C] -> bf16 [C,R] per batch z (R,C multiples of 64)
__global__ void transpose_bf16(const float* __restrict__ src, short* __restrict__ dst,
                               int R, int C) {
  __shared__ float t[64][65];
  long zoff = (long)blockIdx.z * R * C;
  const float* s = src + zoff;
  short* d = dst + zoff;
  int r0 = blockIdx.y * 64, c0 = blockIdx.x * 64;
  int tid = threadIdx.x;
#pragma unroll
  for (int i = 0; i < 16; ++i) {
    int flat = i * 256 + tid;
    int r = flat >> 6, c = flat & 63;
    t[r][c] = s[(long)(r0 + r) * C + c0 + c];
  }
  __syncthreads();
#pragma unroll
  for (int i = 0; i < 16; ++i) {
    int flat = i * 256 + tid;
    int c = flat >> 6, r = flat & 63;
    d[(long)(c0 + c) * R + r0 + r] = f2bf(t[r][c]);
  }
}

// qkv f32 [T,3072] -> Q,K hi/lo [pair][S][dh], Vt hi/lo [pair][dh][S]
__global__ void repack_qkv_split(const float* __restrict__ qkv,
                                 short* __restrict__ Qh, short* __restrict__ Ql,
                                 short* __restrict__ Kh, short* __restrict__ Kl,
                                 short* __restrict__ Vh, short* __restrict__ Vl) {
  long idx = (long)blockIdx.x * 256 + threadIdx.x;
  int t = (int)(idx / 3072), c = (int)(idx % 3072);
  int sec = c >> 10, within = c & 1023;
  int h = within >> 6, di = within & 63;
  int b = t >> 10, s = t & 1023;
  int g = b * NHEADS + h;
  float v = qkv[idx];
  short vh = f2bf(v);
  short vl = f2bf(v - bf2f(vh));
  if (sec == 2) {
    long vo = (long)g * 65536 + di * 1024 + s;
    Vh[vo] = vh; Vl[vo] = vl;
  } else {
    long qo = (long)g * 65536 + s * 64 + di;
    if (sec == 0) { Qh[qo] = vh; Ql[qo] = vl; }
    else          { Kh[qo] = vh; Kl[qo] = vl; }
  }
}

// row softmax on f32, write P as hi plane [0,1024) + lo plane [1024,2048) shorts
__global__ void softmax_rows_split(float* __restrict__ scores) {
  __shared__ float wred[4], wsum[4];
  long row = blockIdx.x;
  float* p = scores + row * 1024;
  int tid = threadIdx.x;
  float4 v = *(const float4*)(p + tid * 4);
  float mx = fmaxf(fmaxf(v.x, v.y), fmaxf(v.z, v.w));
  for (int m = 1; m < 64; m <<= 1) mx = fmaxf(mx, __shfl_xor(mx, m));
  if ((tid & 63) == 0) wred[tid >> 6] = mx;
  __syncthreads();
  mx = fmaxf(fmaxf(wred[0], wred[1]), fmaxf(wred[2], wred[3]));
  float e0 = expf(v.x - mx), e1 = expf(v.y - mx), e2 = expf(v.z - mx), e3 = expf(v.w - mx);
  float sm = e0 + e1 + e2 + e3;
  for (int m = 1; m < 64; m <<= 1) sm += __shfl_xor(sm, m);
  if ((tid & 63) == 0) wsum[tid >> 6] = sm;
  __syncthreads();
  float inv = 1.f / (wsum[0] + wsum[1] + wsum[2] + wsum[3]);
  float y0 = e0 * inv, y1 = e1 * inv, y2 = e2 * inv, y3 = e3 * inv;
  short h0 = f2bf(y0), h1 = f2bf(y1), h2 = f2bf(y2), h3 = f2bf(y3);
  short4v oh = { h0, h1, h2, h3 };
  short4v ol = { f2bf(y0 - bf2f(h0)), f2bf(y1 - bf2f(h1)),
                 f2bf(y2 - bf2f(h2)), f2bf(y3 - bf2f(h3)) };
  short* ps = (short*)p;
  *(short4v*)(ps + tid * 4) = oh;
  *(short4v*)(ps + 1024 + tid * 4) = ol;
}

// layer norm over rows of 1024; optional f32 and bf16 outputs
__global__ void ln_rows(const float* __restrict__ x, const float* __restrict__ g,
                        const float* __restrict__ b, float* __restrict__ of,
                        short* __restrict__ ob) {
  __shared__ float ws1[4], ws2[4];
  long row = blockIdx.x;
  const float* p = x + row * 1024;
  int tid = threadIdx.x;
  float4 v = *(const float4*)(p + tid * 4);
  float s = v.x + v.y + v.z + v.w;
  float s2 = v.x * v.x + v.y * v.y + v.z * v.z + v.w * v.w;
  for (int m = 1; m < 64; m <<= 1) { s += __shfl_xor(s, m); s2 += __shfl_xor(s2, m); }
  if ((tid & 63) == 0) { ws1[tid >> 6] = s; ws2[tid >> 6] = s2; }
  __syncthreads();
  s = ws1[0] + ws1[1] + ws1[2] + ws1[3];
  s2 = ws2[0] + ws2[1] + ws2[2] + ws2[3];
  float mean = s * (1.f / 1024.f);
  float var = s2 * (1.f / 1024.f) - mean * mean;
  float rstd = rsqrtf(var + 1e-5f);
  float4 gg = *(const float4*)(g + tid * 4);
  float4 bb = *(const float4*)(b + tid * 4);
  float y0 = (v.x - mean) * rstd * gg.x + bb.x;
  float y1 = (v.y - mean) * rstd * gg.y + bb.y;
  float y2 = (v.z - mean) * rstd * gg.z + bb.z;
  float y3 = (v.w - mean) * rstd * gg.w + bb.w;
  if (of) { float4 o = { y0, y1, y2, y3 }; *(float4*)(of + row * 1024 + tid * 4) = o; }
  if (ob) { short4v o = { f2bf(y0), f2bf(y1), f2bf(y2), f2bf(y3) }; *(short4v*)(ob + row * 1024 + tid * 4) = o; }
}

// moe combine + LN2: out = LN(accum + g1*y[pos1] + g2*y[pos2])
__global__ void combine_ln2(const float* __restrict__ accum, const float* __restrict__ y,
                            const int* __restrict__ pos1, const int* __restrict__ pos2,
                            const float* __restrict__ g1a, const float* __restrict__ g2a,
                            const float* __restrict__ gn, const float* __restrict__ bn,
                            float* __restrict__ out) {
  __shared__ float ws1[4], ws2[4];
  int t = blockIdx.x;
  int tid = threadIdx.x;
  const float* a = accum + (long)t * 1024;
  const float* y1 = y + (long)pos1[t] * 1024;
  const float* y2 = y + (long)pos2[t] * 1024;
  float G1 = g1a[t], G2 = g2a[t];
  float4 va = *(const float4*)(a + tid * 4);
  float4 v1 = *(const float4*)(y1 + tid * 4);
  float4 v2 = *(const float4*)(y2 + tid * 4);
  float x0 = va.x + G1 * v1.x + G2 * v2.x;
  float x1 = va.y + G1 * v1.y + G2 * v2.y;
  float x2 = va.z + G1 * v1.z + G2 * v2.z;
  float x3 = va.w + G1 * v1.w + G2 * v2.w;
  float s = x0 + x1 + x2 + x3;
  float s2 = x0 * x0 + x1 * x1 + x2 * x2 + x3 * x3;
  for (int m = 1; m < 64; m <<= 1) { s += __shfl_xor(s, m); s2 += __shfl_xor(s2, m); }
  if ((tid & 63) == 0) { ws1[tid >> 6] = s; ws2[tid >> 6] = s2; }
  __syncthreads();
  s = ws1[0] + ws1[1] + ws1[2] + ws1[3];
  s2 = ws2[0] + ws2[1] + ws2[2] + ws2[3];
  float mean = s * (1.f / 1024.f);
  float var = s2 * (1.f / 1024.f) - mean * mean;
  float rstd = rsqrtf(var + 1e-5f);
  float4 gg = *(const float4*)(gn + tid * 4);
  float4 bb = *(const float4*)(bn + tid * 4);
  float4 o = { (x0 - mean) * rstd * gg.x + bb.x,
               (x1 - mean) * rstd * gg.y + bb.y,
               (x2 - mean) * rstd * gg.z + bb.z,
               (x3 - mean) * rstd * gg.w + bb.w };
  *(float4*)(out + (long)t * 1024 + tid * 4) = o;
}

// router pass 1: one wave per token; NO global atomics.
__global__ void router_compute(const float* __restrict__ x, const float* __restrict__ rw,
                               const float* __restrict__ rb,
                               int* __restrict__ top1, int* __restrict__ top2,
                               float* __restrict__ g1o, float* __restrict__ g2o,
                               float* __restrict__ partialP) {
  __shared__ float pp[4][8];
  int w = threadIdx.x >> 6, lane = threadIdx.x & 63;
  int t = blockIdx.x * 4 + w;
  const float* xp = x + (long)t * 1024;
  float xv[16];
#pragma unroll
  for (int i = 0; i < 16; ++i) xv[i] = xp[lane + i * 64];
  float logit[8];
#pragma unroll
  for (int e = 0; e < 8; ++e) {
    const float* wp = rw + e * 1024;
    double a = 0.0;
#pragma unroll
    for (int i = 0; i < 16; ++i) a += (double)xv[i] * (double)wp[lane + i * 64];
    for (int m = 1; m < 64; m <<= 1) a += __shfl_xor(a, m);
    logit[e] = (float)a + rb[e];
  }
  float mx = logit[0];
#pragma unroll
  for (int e = 1; e < 8; ++e) mx = fmaxf(mx, logit[e]);
  float pe[8], sum = 0.f;
#pragma unroll
  for (int e = 0; e < 8; ++e) { pe[e] = expf(logit[e] - mx); sum += pe[e]; }
  float inv = 1.f / sum;
#pragma unroll
  for (int e = 0; e < 8; ++e) pe[e] *= inv;
  int i1 = 0;
#pragma unroll
  for (int e = 1; e < 8; ++e) if (pe[e] > pe[i1]) i1 = e;
  int i2 = (i1 == 0) ? 1 : 0;
#pragma unroll
  for (int e = 0; e < 8; ++e) if (e != i1 && pe[e] > pe[i2]) i2 = e;
  float denom = pe[i1] + pe[i2];
  if (lane == 0) {
    top1[t] = i1; top2[t] = i2;
    g1o[t] = pe[i1] / denom; g2o[t] = pe[i2] / denom;
#pragma unroll
    for (int e = 0; e < 8; ++e) pp[w][e] = pe[e];
  }
  __syncthreads();
  if (threadIdx.x < 8) {
    partialP[(long)blockIdx.x * 8 + threadIdx.x] =
        pp[0][threadIdx.x] + pp[1][threadIdx.x] + pp[2][threadIdx.x] + pp[3][threadIdx.x];
  }
}

// router pass 2 (ONE block, 1024 threads): probsum reduce, counting-sort
// tokens into packed per-expert lists (contention-free), lb loss.
__global__ void __launch_bounds__(1024) router_finalize(
    const float* __restrict__ partialP,
    const int* __restrict__ top1, const int* __restrict__ top2,
    int* __restrict__ counts, int* __restrict__ eoff_out,
    int* __restrict__ tokList, int* __restrict__ pos1, int* __restrict__ pos2,
    float* __restrict__ lb_out) {
  __shared__ float redP[16][8];
  __shared__ int wtot[16][8];
  __shared__ int tot[8], eoff[8];
  __shared__ float psum[8];
  int tid = threadIdx.x;
  int lane = tid & 63, wv = tid >> 6;

  float p[8];
#pragma unroll
  for (int e = 0; e < 8; ++e) p[e] = partialP[(long)tid * 8 + e];
  for (int m = 1; m < 64; m <<= 1)
#pragma unroll
    for (int e = 0; e < 8; ++e) p[e] += __shfl_xor(p[e], m);
  if (lane == 0)
#pragma unroll
    for (int e = 0; e < 8; ++e) redP[wv][e] = p[e];

  int c[8] = {0, 0, 0, 0, 0, 0, 0, 0};
  int expid[8];
#pragma unroll
  for (int j = 0; j < 8; ++j) {
    int i = tid * 8 + j;
    int t = i >> 1;
    int e = (i & 1) ? top2[t] : top1[t];
    expid[j] = e;
    c[e]++;
  }
  int inc[8];
#pragma unroll
  for (int e = 0; e < 8; ++e) inc[e] = c[e];
  for (int d = 1; d < 64; d <<= 1) {
#pragma unroll
    for (int e = 0; e < 8; ++e) {
      int o = __shfl_up(inc[e], d);
      if (lane >= d) inc[e] += o;
    }
  }
  if (lane == 63)
#pragma unroll
    for (int e = 0; e < 8; ++e) wtot[wv][e] = inc[e];
  __syncthreads();
  if (tid < 8) {
    int run = 0;
#pragma unroll
    for (int w = 0; w < 16; ++w) { int v = wtot[w][tid]; wtot[w][tid] = run; run += v; }
    tot[tid] = run;
    float s = 0.f;
#pragma unroll
    for (int w = 0; w < 16; ++w) s += redP[w][tid];
    psum[tid] = s;
  }
  __syncthreads();
  if (tid == 0) {
    int off = 0;
#pragma unroll
    for (int e = 0; e < 8; ++e) { eoff[e] = off; off += tot[e]; }
  }
  __syncthreads();
  int base[8], c2[8] = {0, 0, 0, 0, 0, 0, 0, 0};
#pragma unroll
  for (int e = 0; e < 8; ++e) base[e] = eoff[e] + wtot[wv][e] + inc[e] - c[e];
#pragma unroll
  for (int j = 0; j < 8; ++j) {
    int i = tid * 8 + j;
    int t = i >> 1;
    int e = expid[j];
    int dest = base[e] + c2[e]++;
    tokList[dest] = t;
    if (i & 1) pos2[t] = dest; else pos1[t] = dest;
  }
  if (tid < 8) { counts[tid] = tot[tid]; eoff_out[tid] = eoff[tid]; }
  if (tid == 0) {
    float lb = 0.f;
#pragma unroll
    for (int e = 0; e < 8; ++e)
      lb += ((float)tot[e] / 8192.f) * (psum[e] / 4096.f);
    *lb_out = 8.f * lb;
  }
}

__global__ void sentinel_kernel(float* out, int n) {
  if (threadIdx.x == 0) { out[0] = 1e9f; out[n - 1] = 1e9f; }
}

// ---------------------------------------------------------------------------
extern "C" void kernel_launch(void* const* d_in, const int* in_sizes, int n_in,
                              void* d_out, int out_size, void* d_ws, size_t ws_size,
                              hipStream_t stream) {
  const float* src        = (const float*)d_in[0];
  const float* in_proj_w  = (const float*)d_in[1];
  const float* in_proj_b  = (const float*)d_in[2];
  const float* out_proj_w = (const float*)d_in[3];
  const float* out_proj_b = (const float*)d_in[4];
  const float* ln1_g      = (const float*)d_in[5];
  const float* ln1_b      = (const float*)d_in[6];
  const float* router_w   = (const float*)d_in[7];
  const float* router_b   = (const float*)d_in[8];
  const float* w1         = (const float*)d_in[9];
  const float* b1         = (const float*)d_in[10];
  const float* w2         = (const float*)d_in[11];
  const float* b2         = (const float*)d_in[12];
  const float* ln2_g      = (const float*)d_in[13];
  const float* ln2_b      = (const float*)d_in[14];
  float* out = (float*)d_out;

  char* ws = (char*)d_ws;
  size_t off = 0;
  auto alloc = [&](size_t bytes) -> char* {
    char* p = ws + off;
    off += (bytes + 255) & ~(size_t)255;
    return p;
  };
  // big block: Q/K/V hi+lo planes during attention; w1t/w2t after
  char*  blockW = alloc(8ll * (DFF * DMODEL + DMODEL * DFF) * 2);  // 128MB
  short* Qh = (short*)(blockW + 0ll  * 1024 * 1024);
  short* Ql = (short*)(blockW + 8ll  * 1024 * 1024);
  short* Kh = (short*)(blockW + 16ll * 1024 * 1024);
  short* Kl = (short*)(blockW + 24ll * 1024 * 1024);
  short* Vh = (short*)(blockW + 32ll * 1024 * 1024);
  short* Vl = (short*)(blockW + 40ll * 1024 * 1024);
  short* w1t = (short*)blockW;                                      // [E][dff][d]
  short* w2t = (short*)(blockW + 8ll * DFF * DMODEL * 2);           // [E][d][dff]
  short* winh  = (short*)alloc(3072ll * 1024 * 2);
  short* winl  = (short*)alloc(3072ll * 1024 * 2);
  short* wouth = (short*)alloc(1024ll * 1024 * 2);
  short* woutl = (short*)alloc(1024ll * 1024 * 2);
  short* xh    = (short*)alloc((long)TOKENS * DMODEL * 2);
  short* xl    = (short*)alloc((long)TOKENS * DMODEL * 2);
  char*  reg1  = alloc((long)TOKENS * 3072 * 4);     // 48MB: qkv f32 -> O planes/x1 -> y
  float* qkvf  = (float*)reg1;
  float* Of32  = (float*)reg1;
  short* Ohi   = (short*)(reg1 + 16ll * 1024 * 1024);
  short* Olo   = (short*)(reg1 + 24ll * 1024 * 1024);
  float* x1    = (float*)(reg1 + 32ll * 1024 * 1024);
  float* y     = (float*)reg1;                       // packed expert outputs [8192,1024] f32
  char*  reg2  = alloc(16ll * 1024 * 1024 * 4);      // 64MB: scores chunk -> h
  float* scores = (float*)reg2;
  short* h      = (short*)reg2;
  short* x1nbf = (short*)alloc((long)TOKENS * DMODEL * 2);
  float* accum = (float*)alloc((long)TOKENS * DMODEL * 4);
  float* partialP = (float*)alloc(1024 * 8 * 4);
  int*   top1   = (int*)alloc(TOKENS * 4);
  int*   top2   = (int*)alloc(TOKENS * 4);
  float* g1a    = (float*)alloc(TOKENS * 4);
  float* g2a    = (float*)alloc(TOKENS * 4);
  int*   pos1   = (int*)alloc(TOKENS * 4);
  int*   pos2   = (int*)alloc(TOKENS * 4);
  int*   counts = (int*)alloc(32);
  int*   eoff   = (int*)alloc(32);
  int*   tokList = (int*)alloc(2 * TOKENS * 4);
  size_t needed = off;

  if (ws_size < needed) {
    sentinel_kernel<<<1, 64, 0, stream>>>(out, out_size);
    return;
  }

  // splits of f32 inputs
  split_bf16<<<3072 * 1024 / 1024, 256, 0, stream>>>(in_proj_w, winh, winl, 3072 * 1024);
  split_bf16<<<1024 * 1024 / 1024, 256, 0, stream>>>(out_proj_w, wouth, woutl, 1024 * 1024);
  split_bf16<<<TOKENS * DMODEL / 1024, 256, 0, stream>>>(src, xh, xl, TOKENS * DMODEL);

  // QKV projection (split): qkv f32 = x @ win^T + b
  gemm_nt<128, 128, 64, 64, 1, 0, false, true><<<dim3(32, 24, 1), 256, 0, stream>>>(
      xh, xl, 1024, 0, winh, winl, 1024, 0, qkvf, 3072, 0,
      TOKENS, 3072, 1024, 1.f, in_proj_b, 0, nullptr, nullptr, nullptr, nullptr);
  repack_qkv_split<<<(int)((long)TOKENS * 3072 / 256), 256, 0, stream>>>(qkvf, Qh, Ql, Kh, Kl, Vh, Vl);

  // attention, chunked by batch (16 pairs per chunk)
  for (int c = 0; c < 4; ++c) {
    long co = (long)c * 16 * 65536;
    gemm_nt<128, 128, 64, 64, 1, 0, false, true><<<dim3(8, 8, 16), 256, 0, stream>>>(
        Qh + co, Ql + co, 64, 65536, Kh + co, Kl + co, 64, 65536, scores, 1024, 1048576,
        1024, 1024, 64, 0.125f, nullptr, 0, nullptr, nullptr, nullptr, nullptr);
    softmax_rows_split<<<16 * 1024, 256, 0, stream>>>(scores);
    // P(hi/lo in place, pitch 2048 shorts) @ V^T -> O f32
    gemm_nt<128, 64, 64, 32, 1, 0, false, true><<<dim3(8, 1, 16), 256, 0, stream>>>(
        (const short*)scores, (const short*)scores + 1024, 2048, 2097152,
        Vh + co, Vl + co, 1024, 65536,
        Of32 + (long)c * 1048576, 1024, 64,
        1024, 64, 1024, 1.f, nullptr, 0, nullptr, nullptr, nullptr, nullptr);
  }

  // expert weight transposes now (blockW's Q/K/V no longer needed)
  transpose_bf16<<<dim3(DFF / 64, DMODEL / 64, 8), 256, 0, stream>>>(w1, w1t, DMODEL, DFF);
  transpose_bf16<<<dim3(DMODEL / 64, DFF / 64, 8), 256, 0, stream>>>(w2, w2t, DFF, DMODEL);

  // split O, then out-projection (split) + bias + residual(src) -> x1 f32
  split_bf16<<<TOKENS * DMODEL / 1024, 256, 0, stream>>>(Of32, Ohi, Olo, TOKENS * DMODEL);
  gemm_nt<128, 128, 64, 64, 1, 0, false, true><<<dim3(32, 8, 1), 256, 0, stream>>>(
      Ohi, Olo, 1024, 0, wouth, woutl, 1024, 0, x1, 1024, 0,
      TOKENS, 1024, 1024, 1.f, out_proj_b, 0, src, nullptr, nullptr, nullptr);

  // LN1 -> accum (f32 residual base) + x1nbf (bf16 expert input)
  ln_rows<<<TOKENS, 256, 0, stream>>>(x1, ln1_g, ln1_b, accum, x1nbf);

  // router (atomic-free)
  router_compute<<<TOKENS / 4, 256, 0, stream>>>(accum, router_w, router_b,
                                                 top1, top2, g1a, g2a, partialP);
  router_finalize<<<1, 1024, 0, stream>>>(partialP, top1, top2, counts, eoff,
                                          tokList, pos1, pos2, out + (out_size - 1));

  // expert GEMM1: h = relu(gather(x1nbf) @ w1t[e]^T + b1[e]) (packed bf16)
  gemm_nt<128, 128, 64, 64, 0, 1, true, false><<<dim3(32, 32, 8), 256, 0, stream>>>(
      x1nbf, nullptr, 1024, 0, w1t, nullptr, 1024, (long)DFF * DMODEL, h, DFF, 0,
      0, DFF, 1024, 1.f, b1, DFF, nullptr, tokList, counts, eoff);

  // expert GEMM2: y[packed] = h @ w2t[e]^T + b2[e]  (f32 store, no atomics)
  gemm_nt<128, 128, 64, 64, 1, 2, false, false><<<dim3(32, 8, 8), 256, 0, stream>>>(
      h, nullptr, DFF, 0, w2t, nullptr, DFF, (long)DMODEL * DFF, y, 1024, 0,
      0, DMODEL, DFF, 1.f, b2, DMODEL, nullptr, tokList, counts, eoff);

  // combine + LN2 -> final output
  combine_ln2<<<TOKENS, 256, 0, stream>>>(accum, y, pos1, pos2, g1a, g2a,
                                          ln2_g, ln2_b, out);
}

// Round 5
// 956.071 us; speedup vs baseline: 1.7231x; 1.2174x over previous
//
#include <hip/hip_runtime.h>

// ---------------------------------------------------------------------------
// TransformerEncoderLayerWithMoE on MI355X (gfx950)
// Round 9: fused flash attention. R4's XCD remap fixed the expert GEMMs
// (273->53MB fetch, total 1529->1164us). Remaining fat: the attention
// middle materializes scores f32 (67MB/chunk) + softmax r/w + P-plane
// read, ~1GB of round-trip traffic over 12 dispatches, and PV ran on a
// 128-block grid (half the GPU idle). This round fuses QK^T -> online
// softmax -> PV into one kernel (512 blocks, 4 waves, per-wave 32 q-rows):
//   - Q hi/lo fragments in registers (loaded once)
//   - K / V^T tiles (64 kv) staged hi/lo via global_load_lds with
//     row-XOR chunk swizzle (conflict-free b128 frag reads)
//   - S in f32 MFMA accumulators, scaled 1/8; online softmax with
//     16-lane shfl_xor row reduces (exact same arithmetic as 3-pass)
//   - P-hat split to hi/lo bf16 via per-wave LDS (rows padded to 72
//     shorts: aligned + conflict-free) to turn C-layout into A-layout
//   - 3-term split MFMAs for QK and PV (same precision as before)
//   - epilogue divides by l and writes Ohi/Olo directly (split pass gone)
// ---------------------------------------------------------------------------

typedef __attribute__((ext_vector_type(8))) short short8;   // 8 bf16 = 4 VGPRs
typedef __attribute__((ext_vector_type(4))) short short4v;
typedef __attribute__((ext_vector_type(4))) float floatx4;  // MFMA C/D frag

#define TOKENS 4096
#define DMODEL 1024
#define NHEADS 16
#define DHEAD  64
#define DFF    4096
#define NEXP   8
#define SEQ    1024
#define NPAIR  64   // BATCH*NHEADS

// RNE float->bf16 (finite inputs only)
__device__ inline short f2bf(float f) {
  unsigned u = __builtin_bit_cast(unsigned, f);
  unsigned r = (u + 0x7fffu + ((u >> 16) & 1u)) >> 16;
  return (short)r;
}
__device__ inline float bf2f(short h) {
  return __builtin_bit_cast(float, ((unsigned)(unsigned short)h) << 16);
}

// async 16B/lane global->LDS DMA; lds dest = wave-uniform base + lane*16
__device__ inline void gload16(const short* g, short* l) {
  __builtin_amdgcn_global_load_lds(
      (const __attribute__((address_space(1))) unsigned int*)g,
      (__attribute__((address_space(3))) unsigned int*)l, 16, 0, 0);
}

// ---------------------------------------------------------------------------
// NT GEMM: C[m,n] = scale * sum_k A[m,k]*B[n,k] (+bias[n]) (+src)
// SPLIT: A/B given as hi+lo bf16 planes; acc += Ah*Bh + Ah*Bl + Al*Bh
// EPI: 0 = bf16 store, 1 = f32 store (+optional srcadd)
// AMODE: 0 = linear rows, 1 = gathered rows via packed tokList, 2 = offset rows
// LDS layout: unpadded [rows][32] shorts, 16B chunk c of row r stored at
// chunk position c ^ (r&3) ^ ((r>>2)&3)  (bank-conflict-free, DMA-compatible)
// Double-buffered R1 schedule: compute(t); stage(t+1); __syncthreads().
// XCD-locality remap (R4, measured 273->53MB fetch on GEMM1):
//   AMODE!=0: expert e on dispatch positions == e (mod 8)
//   AMODE==0: contiguous chunk per XCD within each z
// ---------------------------------------------------------------------------
template<int BM, int BN, int WTM, int WTN, int EPI, int AMODE, bool RELU, bool SPLIT>
__global__ void __launch_bounds__((BM / WTM) * (BN / WTN) * 64)
gemm_nt(const short* __restrict__ Ab, const short* __restrict__ Abl, int lda, long sA,
        const short* __restrict__ Bb, const short* __restrict__ Bbl, int ldb, long sB,
        void* __restrict__ Cb, int ldc, long sC,
        int M, int N, int K, float scale,
        const float* __restrict__ bias, int sBias,
        const float* __restrict__ srcadd,
        const int* __restrict__ tokList,
        const int* __restrict__ counts,
        const int* __restrict__ offsets)
{
  constexpr int WROWS = BM / WTM;
  constexpr int WCOLS = BN / WTN;
  constexpr int NW = WROWS * WCOLS;
  constexpr int MT = WTM / 16;
  constexpr int NT = WTN / 16;
  constexpr int ISSA = (BM / 16) / NW;   // 1024B (16 rows) per wave-issue
  constexpr int ISSB = (BN / 16) / NW;
  constexpr int PL = SPLIT ? 2 : 1;
  constexpr int ABUF = PL * BM * 32;     // shorts per A buffer
  constexpr int BBUF = PL * BN * 32;     // shorts per B buffer

  // --- XCD-locality work remap (dispatch position % 8 ~ XCD) ---
  int xw, yw, zw;
  if (AMODE != 0) {
    int flat = blockIdx.x + gridDim.x * (blockIdx.y + gridDim.y * blockIdx.z);
    zw = flat & 7;                       // expert = XCD residue
    int m = flat >> 3;
    xw = m % gridDim.x;
    yw = m / gridDim.x;
  } else {
    int nwg = gridDim.x * gridDim.y;
    int f2 = blockIdx.x + gridDim.x * blockIdx.y;
    int cpx = nwg >> 3;
    int g = (f2 & 7) * cpx + (f2 >> 3);
    xw = g % gridDim.x;
    yw = g / gridDim.x;
    zw = blockIdx.z;
  }

  const int z = zw;
  int Mt = M;
  int rowbase = 0;
  const int* tl = nullptr;
  if (AMODE != 0) {
    Mt = counts[z];
    if (xw * BM >= Mt) return;
    if (AMODE == 1) tl = tokList + offsets[z];
    else rowbase = offsets[z];
  }

  const short* A = Ab + (long)z * sA;
  const short* Al = SPLIT ? (Abl + (long)z * sA) : nullptr;
  const short* B = Bb + (long)z * sB;
  const short* Bl = SPLIT ? (Bbl + (long)z * sB) : nullptr;
  const int tid = threadIdx.x;
  const int lane = tid & 63;
  const int w = tid >> 6;
  const int wrow = w % WROWS;
  const int wcol = w / WROWS;
  const int m0 = xw * BM;
  const int n0 = yw * BN;

  __shared__ __align__(16) short As[2 * ABUF];
  __shared__ __align__(16) short Bs[2 * BBUF];

  const int l4 = lane >> 2;                               // row in segment
  const int lc = (lane & 3) ^ (l4 & 3) ^ ((lane >> 4) & 3); // source 16B chunk
  long agp[ISSA]; int albase[ISSA];
#pragma unroll
  for (int r = 0; r < ISSA; ++r) {
    int seg = w * ISSA + r;
    int row = seg * 16 + l4;
    int grow;
    if (AMODE == 0) grow = m0 + row;
    else if (AMODE == 1) grow = tl[min(m0 + row, Mt - 1)];
    else grow = rowbase + min(m0 + row, Mt - 1);
    agp[r] = (long)grow * lda + lc * 8;
    albase[r] = seg * 512;
  }
  long bgp[ISSB]; int blbase[ISSB];
#pragma unroll
  for (int r = 0; r < ISSB; ++r) {
    int seg = w * ISSB + r;
    int row = seg * 16 + l4;
    bgp[r] = (long)(n0 + row) * ldb + lc * 8;
    blbase[r] = seg * 512;
  }

  floatx4 acc[MT][NT];
#pragma unroll
  for (int i = 0; i < MT; ++i)
#pragma unroll
    for (int j = 0; j < NT; ++j) acc[i][j] = floatx4{0.f, 0.f, 0.f, 0.f};

  const int am = wrow * WTM + (lane & 15);
  const int bn = wcol * WTN + (lane & 15);
  const int ac = lane >> 4;
  const int aro = am * 32 + ((ac ^ (am & 3) ^ ((am >> 2) & 3)) << 3);
  const int bro = bn * 32 + ((ac ^ (bn & 3) ^ ((bn >> 2) & 3)) << 3);

  auto stage = [&](int buf, int k0) {
    short* Ad = &As[buf * ABUF];
    short* Bd = &Bs[buf * BBUF];
#pragma unroll
    for (int r = 0; r < ISSA; ++r) gload16(A + agp[r] + k0, Ad + albase[r]);
#pragma unroll
    for (int r = 0; r < ISSB; ++r) gload16(B + bgp[r] + k0, Bd + blbase[r]);
    if (SPLIT) {
#pragma unroll
      for (int r = 0; r < ISSA; ++r) gload16(Al + agp[r] + k0, Ad + BM * 32 + albase[r]);
#pragma unroll
      for (int r = 0; r < ISSB; ++r) gload16(Bl + bgp[r] + k0, Bd + BN * 32 + blbase[r]);
    }
  };

  auto compute = [&](int buf) {
    const short* Ar = &As[buf * ABUF];
    const short* Br = &Bs[buf * BBUF];
    short8 afh[MT], bfh[NT];
#pragma unroll
    for (int i = 0; i < MT; ++i) afh[i] = *(const short8*)&Ar[aro + i * 512];
#pragma unroll
    for (int j = 0; j < NT; ++j) bfh[j] = *(const short8*)&Br[bro + j * 512];
    if (SPLIT) {
      short8 afl[MT], bfl[NT];
#pragma unroll
      for (int i = 0; i < MT; ++i) afl[i] = *(const short8*)&Ar[BM * 32 + aro + i * 512];
#pragma unroll
      for (int j = 0; j < NT; ++j) bfl[j] = *(const short8*)&Br[BN * 32 + bro + j * 512];
#pragma unroll
      for (int i = 0; i < MT; ++i)
#pragma unroll
        for (int j = 0; j < NT; ++j) {
          acc[i][j] = __builtin_amdgcn_mfma_f32_16x16x32_bf16(afh[i], bfh[j], acc[i][j], 0, 0, 0);
          acc[i][j] = __builtin_amdgcn_mfma_f32_16x16x32_bf16(afh[i], bfl[j], acc[i][j], 0, 0, 0);
          acc[i][j] = __builtin_amdgcn_mfma_f32_16x16x32_bf16(afl[i], bfh[j], acc[i][j], 0, 0, 0);
        }
    } else {
#pragma unroll
      for (int i = 0; i < MT; ++i)
#pragma unroll
        for (int j = 0; j < NT; ++j)
          acc[i][j] = __builtin_amdgcn_mfma_f32_16x16x32_bf16(afh[i], bfh[j], acc[i][j], 0, 0, 0);
    }
  };

  const int ntile = K >> 5;           // k-steps of 32
  stage(0, 0);
  __syncthreads();
  int cur = 0;
  for (int t = 0; t < ntile - 1; ++t) {
    compute(cur);
    stage(cur ^ 1, (t + 1) << 5);
    __syncthreads();
    cur ^= 1;
  }
  compute(cur);

  // epilogue: C layout col=lane&15, row=(lane>>4)*4+q
  const float* bz = bias ? (bias + (long)z * sBias) : nullptr;
#pragma unroll
  for (int i = 0; i < MT; ++i) {
    int rt = wrow * WTM + i * 16 + ((lane >> 4) << 2);
#pragma unroll
    for (int j = 0; j < NT; ++j) {
      int col = n0 + wcol * WTN + j * 16 + (lane & 15);
      float badd = bz ? bz[col] : 0.f;
      floatx4 v = acc[i][j];
#pragma unroll
      for (int q = 0; q < 4; ++q) {
        int r = m0 + rt + q;
        if (AMODE != 0 && r >= Mt) break;
        long orow = (AMODE == 1) ? ((long)offsets[z] + r)
                  : (AMODE == 2) ? ((long)rowbase + r) : (long)r;
        float val = v[q] * scale + badd;
        if (RELU) val = fmaxf(val, 0.f);
        if (EPI == 0) {
          ((short*)Cb)[(long)z * sC + orow * ldc + col] = f2bf(val);
        } else {
          float* Cf = (float*)Cb + (long)z * sC;
          if (srcadd) val += srcadd[orow * ldc + col];
          Cf[orow * ldc + col] = val;
        }
      }
    }
  }
}

// ---------------------------------------------------------------------------
// Fused flash attention: per block = one (pair, 128-q-row tile).
// grid (8,1,64), 256 threads (4 waves x 32 q-rows each). dh=64, S=1024.
// Numerics identical to the 3-pass path: split-bf16 3-term QK and PV MFMAs,
// f32 softmax (online, renormalized by l at the end).
// ---------------------------------------------------------------------------
__global__ void __launch_bounds__(256)
fused_attn(const short* __restrict__ Qh, const short* __restrict__ Ql,
           const short* __restrict__ Kh, const short* __restrict__ Kl,
           const short* __restrict__ Vh, const short* __restrict__ Vl,
           short* __restrict__ Ohi, short* __restrict__ Olo)
{
  // XCD-locality remap: the 8 q-tiles of a pair share K/V -> same XCD residue
  const int f = blockIdx.x + 8 * blockIdx.z;          // [0,512)
  const int pair = (f & 7) + ((f >> 6) << 3);         // bijective
  const int qt = (f >> 3) & 7;
  const long pb = (long)pair * 65536;                 // 1024*64
  const int lane = threadIdx.x & 63;
  const int w = threadIdx.x >> 6;                     // wave 0..3
  const int qb0 = qt * 128;

  __shared__ __align__(16) short Ksh[4096], Ksl[4096];  // [kv 64][d 64] swz
  __shared__ __align__(16) short Vsh[4096], Vsl[4096];  // [d 64][kv 64] swz
  __shared__ __align__(16) short Ph[4][32 * 72], Pl[4][32 * 72]; // padded

  // Q fragments in registers: rows w*32 + i*16 + (lane&15), k=d
  short8 qfh[2][2], qfl[2][2];
#pragma unroll
  for (int i = 0; i < 2; ++i)
#pragma unroll
    for (int kt = 0; kt < 2; ++kt) {
      long qoff = pb + (long)(qb0 + w * 32 + i * 16 + (lane & 15)) * 64
                + (lane >> 4) * 8 + kt * 32;
      qfh[i][kt] = *(const short8*)&Qh[qoff];
      qfl[i][kt] = *(const short8*)&Ql[qoff];
    }

  floatx4 oacc[2][4];
#pragma unroll
  for (int i = 0; i < 2; ++i)
#pragma unroll
    for (int jd = 0; jd < 4; ++jd) oacc[i][jd] = floatx4{0.f, 0.f, 0.f, 0.f};
  float mrow[2][4], lrow[2][4];
#pragma unroll
  for (int i = 0; i < 2; ++i)
#pragma unroll
    for (int q = 0; q < 4; ++q) { mrow[i][q] = -1e30f; lrow[i][q] = 0.f; }

  // staging lane map: 8 rows x 8 chunks per issue; source chunk XOR-swizzled
  const int r8 = lane >> 3, pc8 = lane & 7;
  const int lc8 = ((pc8 ^ r8) & 7) * 8;   // (pc ^ (r&7))*8, r<8 so r&7==r

  for (int t = 0; t < 16; ++t) {
    const int kv0 = t * 64;
    __syncthreads();                      // prior-tile LDS reads complete
#pragma unroll
    for (int s = 0; s < 2; ++s) {
      int seg = w * 2 + s;                // 8 segs over 4 waves
      long krow = kv0 + seg * 8 + r8;
      gload16(&Kh[pb + krow * 64 + lc8], &Ksh[seg * 512]);
      gload16(&Kl[pb + krow * 64 + lc8], &Ksl[seg * 512]);
      long drow = seg * 8 + r8;
      gload16(&Vh[pb + drow * 1024 + kv0 + lc8], &Vsh[seg * 512]);
      gload16(&Vl[pb + drow * 1024 + kv0 + lc8], &Vsl[seg * 512]);
    }
    __syncthreads();                      // implicit vmcnt(0): tile staged

    // S = Q K^T (split 3-term): per wave 32 rows x 64 kv cols
    floatx4 sacc[2][4];
#pragma unroll
    for (int i = 0; i < 2; ++i)
#pragma unroll
      for (int j = 0; j < 4; ++j) sacc[i][j] = floatx4{0.f, 0.f, 0.f, 0.f};
#pragma unroll
    for (int j = 0; j < 4; ++j) {
      int rr = j * 16 + (lane & 15);
      int base = rr * 64, rsw = rr & 7;
#pragma unroll
      for (int kt = 0; kt < 2; ++kt) {
        int kc = (lane >> 4) + kt * 4;
        int off = base + ((kc ^ rsw) << 3);
        short8 kh8 = *(const short8*)&Ksh[off];
        short8 kl8 = *(const short8*)&Ksl[off];
#pragma unroll
        for (int i = 0; i < 2; ++i) {
          sacc[i][j] = __builtin_amdgcn_mfma_f32_16x16x32_bf16(qfh[i][kt], kh8, sacc[i][j], 0, 0, 0);
          sacc[i][j] = __builtin_amdgcn_mfma_f32_16x16x32_bf16(qfh[i][kt], kl8, sacc[i][j], 0, 0, 0);
          sacc[i][j] = __builtin_amdgcn_mfma_f32_16x16x32_bf16(qfl[i][kt], kh8, sacc[i][j], 0, 0, 0);
        }
      }
    }
#pragma unroll
    for (int i = 0; i < 2; ++i)
#pragma unroll
      for (int j = 0; j < 4; ++j) sacc[i][j] *= 0.125f;

    // online softmax: rows live in-lane as (i,q); cols across lane&15 + j
#pragma unroll
    for (int i = 0; i < 2; ++i)
#pragma unroll
      for (int q = 0; q < 4; ++q) {
        float tm = fmaxf(fmaxf(sacc[i][0][q], sacc[i][1][q]),
                         fmaxf(sacc[i][2][q], sacc[i][3][q]));
#pragma unroll
        for (int msk = 1; msk < 16; msk <<= 1) tm = fmaxf(tm, __shfl_xor(tm, msk));
        float mold = mrow[i][q];
        float mn = fmaxf(mold, tm);
        float c = expf(mold - mn);
        mrow[i][q] = mn;
        float ts = 0.f;
#pragma unroll
        for (int j = 0; j < 4; ++j) {
          float p = expf(sacc[i][j][q] - mn);
          sacc[i][j][q] = p;
          ts += p;
        }
#pragma unroll
        for (int msk = 1; msk < 16; msk <<= 1) ts += __shfl_xor(ts, msk);
        lrow[i][q] = lrow[i][q] * c + ts;
#pragma unroll
        for (int jd = 0; jd < 4; ++jd) oacc[i][jd][q] *= c;
      }

    // P-hat -> bf16 hi/lo, C-layout -> LDS (per-wave, padded rows)
    short* php = Ph[w];
    short* plp = Pl[w];
#pragma unroll
    for (int i = 0; i < 2; ++i)
#pragma unroll
      for (int j = 0; j < 4; ++j)
#pragma unroll
        for (int q = 0; q < 4; ++q) {
          float p = sacc[i][j][q];
          short ph_ = f2bf(p);
          short pl_ = f2bf(p - bf2f(ph_));
          int row = i * 16 + ((lane >> 4) << 2) + q;
          int col = j * 16 + (lane & 15);
          php[row * 72 + col] = ph_;
          plp[row * 72 + col] = pl_;
        }
    asm volatile("s_waitcnt lgkmcnt(0)" ::: "memory");
    __builtin_amdgcn_sched_barrier(0);

    // P A-frags (rows q, k=kv)
    short8 pah[2][2], pal[2][2];
#pragma unroll
    for (int i = 0; i < 2; ++i)
#pragma unroll
      for (int kt = 0; kt < 2; ++kt) {
        int off = (i * 16 + (lane & 15)) * 72 + (lane >> 4) * 8 + kt * 32;
        pah[i][kt] = *(const short8*)&php[off];
        pal[i][kt] = *(const short8*)&plp[off];
      }
    // O += P V^T (split 3-term)
#pragma unroll
    for (int jd = 0; jd < 4; ++jd) {
      int rr = jd * 16 + (lane & 15);
      int base = rr * 64, rsw = rr & 7;
#pragma unroll
      for (int kt = 0; kt < 2; ++kt) {
        int kc = (lane >> 4) + kt * 4;
        int off = base + ((kc ^ rsw) << 3);
        short8 vh8 = *(const short8*)&Vsh[off];
        short8 vl8 = *(const short8*)&Vsl[off];
#pragma unroll
        for (int i = 0; i < 2; ++i) {
          oacc[i][jd] = __builtin_amdgcn_mfma_f32_16x16x32_bf16(pah[i][kt], vh8, oacc[i][jd], 0, 0, 0);
          oacc[i][jd] = __builtin_amdgcn_mfma_f32_16x16x32_bf16(pah[i][kt], vl8, oacc[i][jd], 0, 0, 0);
          oacc[i][jd] = __builtin_amdgcn_mfma_f32_16x16x32_bf16(pal[i][kt], vh8, oacc[i][jd], 0, 0, 0);
        }
      }
    }
  }

  // epilogue: O = oacc / l, write hi/lo planes directly
  const int b = pair >> 4, hh = pair & 15;
#pragma unroll
  for (int i = 0; i < 2; ++i)
#pragma unroll
    for (int q = 0; q < 4; ++q) {
      float inv = 1.f / lrow[i][q];
      int qrow = qb0 + w * 32 + i * 16 + ((lane >> 4) << 2) + q;
      long obase = (long)(b * 1024 + qrow) * 1024 + hh * 64;
#pragma unroll
      for (int jd = 0; jd < 4; ++jd) {
        float v = oacc[i][jd][q] * inv;
        short vh_ = f2bf(v);
        long oi = obase + jd * 16 + (lane & 15);
        Ohi[oi] = vh_;
        Olo[oi] = f2bf(v - bf2f(vh_));
      }
    }
}

// f32 -> hi/lo bf16 planes
__global__ void split_bf16(const float* __restrict__ src, short* __restrict__ hi,
                           short* __restrict__ lo, int n) {
  int i = (blockIdx.x * 256 + threadIdx.x) * 4;
  if (i >= n) return;
  float4 v = *(const float4*)(src + i);
  short h0 = f2bf(v.x), h1 = f2bf(v.y), h2 = f2bf(v.z), h3 = f2bf(v.w);
  short4v oh = { h0, h1, h2, h3 };
  short4v ol = { f2bf(v.x - bf2f(h0)), f2bf(v.y - bf2f(h1)),
                 f2bf(v.z - bf2f(h2)), f2bf(v.w - bf2f(h3)) };
  *(short4v*)(hi + i) = oh;
  *(short4v*)(lo + i) = ol;
}

// f32 [R,C] -> bf16 [C,R] per batch z (R,C multiples of 64)
__global__ void transpose_bf16(const float* __restrict__ src, short* __restrict__ dst,
                               int R, int C) {
  __shared__ float t[64][65];
  long zoff = (long)blockIdx.z * R * C;
  const float* s = src + zoff;
  short* d = dst + zoff;
  int r0 = blockIdx.y * 64, c0 = blockIdx.x * 64;
  int tid = threadIdx.x;
#pragma unroll
  for (int i = 0; i < 16; ++i) {
    int flat = i * 256 + tid;
    int r = flat >> 6, c = flat & 63;
    t[r][c] = s[(long)(r0 + r) * C + c0 + c];
  }
  __syncthreads();
#pragma unroll
  for (int i = 0; i < 16; ++i) {
    int flat = i * 256 + tid;
    int c = flat >> 6, r = flat & 63;
    d[(long)(c0 + c) * R + r0 + r] = f2bf(t[r][c]);
  }
}

// qkv f32 [T,3072] -> Q,K hi/lo [pair][S][dh], Vt hi/lo [pair][dh][S]
__global__ void repack_qkv_split(const float* __restrict__ qkv,
                                 short* __restrict__ Qh, short* __restrict__ Ql,
                                 short* __restrict__ Kh, short* __restrict__ Kl,
                                 short* __restrict__ Vh, short* __restrict__ Vl) {
  long idx = (long)blockIdx.x * 256 + threadIdx.x;
  int t = (int)(idx / 3072), c = (int)(idx % 3072);
  int sec = c >> 10, within = c & 1023;
  int h = within >> 6, di = within & 63;
  int b = t >> 10, s = t & 1023;
  int g = b * NHEADS + h;
  float v = qkv[idx];
  short vh = f2bf(v);
  short vl = f2bf(v - bf2f(vh));
  if (sec == 2) {
    long vo = (long)g * 65536 + di * 1024 + s;
    Vh[vo] = vh; Vl[vo] = vl;
  } else {
    long qo = (long)g * 65536 + s * 64 + di;
    if (sec == 0) { Qh[qo] = vh; Ql[qo] = vl; }
    else          { Kh[qo] = vh; Kl[qo] = vl; }
  }
}

// layer norm over rows of 1024; optional f32 and bf16 outputs
__global__ void ln_rows(const float* __restrict__ x, const float* __restrict__ g,
                        const float* __restrict__ b, float* __restrict__ of,
                        short* __restrict__ ob) {
  __shared__ float ws1[4], ws2[4];
  long row = blockIdx.x;
  const float* p = x + row * 1024;
  int tid = threadIdx.x;
  float4 v = *(const float4*)(p + tid * 4);
  float s = v.x + v.y + v.z + v.w;
  float s2 = v.x * v.x + v.y * v.y + v.z * v.z + v.w * v.w;
  for (int m = 1; m < 64; m <<= 1) { s += __shfl_xor(s, m); s2 += __shfl_xor(s2, m); }
  if ((tid & 63) == 0) { ws1[tid >> 6] = s; ws2[tid >> 6] = s2; }
  __syncthreads();
  s = ws1[0] + ws1[1] + ws1[2] + ws1[3];
  s2 = ws2[0] + ws2[1] + ws2[2] + ws2[3];
  float mean = s * (1.f / 1024.f);
  float var = s2 * (1.f / 1024.f) - mean * mean;
  float rstd = rsqrtf(var + 1e-5f);
  float4 gg = *(const float4*)(g + tid * 4);
  float4 bb = *(const float4*)(b + tid * 4);
  float y0 = (v.x - mean) * rstd * gg.x + bb.x;
  float y1 = (v.y - mean) * rstd * gg.y + bb.y;
  float y2 = (v.z - mean) * rstd * gg.z + bb.z;
  float y3 = (v.w - mean) * rstd * gg.w + bb.w;
  if (of) { float4 o = { y0, y1, y2, y3 }; *(float4*)(of + row * 1024 + tid * 4) = o; }
  if (ob) { short4v o = { f2bf(y0), f2bf(y1), f2bf(y2), f2bf(y3) }; *(short4v*)(ob + row * 1024 + tid * 4) = o; }
}

// moe combine + LN2: out = LN(accum + g1*y[pos1] + g2*y[pos2])
__global__ void combine_ln2(const float* __restrict__ accum, const float* __restrict__ y,
                            const int* __restrict__ pos1, const int* __restrict__ pos2,
                            const float* __restrict__ g1a, const float* __restrict__ g2a,
                            const float* __restrict__ gn, const float* __restrict__ bn,
                            float* __restrict__ out) {
  __shared__ float ws1[4], ws2[4];
  int t = blockIdx.x;
  int tid = threadIdx.x;
  const float* a = accum + (long)t * 1024;
  const float* y1 = y + (long)pos1[t] * 1024;
  const float* y2 = y + (long)pos2[t] * 1024;
  float G1 = g1a[t], G2 = g2a[t];
  float4 va = *(const float4*)(a + tid * 4);
  float4 v1 = *(const float4*)(y1 + tid * 4);
  float4 v2 = *(const float4*)(y2 + tid * 4);
  float x0 = va.x + G1 * v1.x + G2 * v2.x;
  float x1 = va.y + G1 * v1.y + G2 * v2.y;
  float x2 = va.z + G1 * v1.z + G2 * v2.z;
  float x3 = va.w + G1 * v1.w + G2 * v2.w;
  float s = x0 + x1 + x2 + x3;
  float s2 = x0 * x0 + x1 * x1 + x2 * x2 + x3 * x3;
  for (int m = 1; m < 64; m <<= 1) { s += __shfl_xor(s, m); s2 += __shfl_xor(s2, m); }
  if ((tid & 63) == 0) { ws1[tid >> 6] = s; ws2[tid >> 6] = s2; }
  __syncthreads();
  s = ws1[0] + ws1[1] + ws1[2] + ws1[3];
  s2 = ws2[0] + ws2[1] + ws2[2] + ws2[3];
  float mean = s * (1.f / 1024.f);
  float var = s2 * (1.f / 1024.f) - mean * mean;
  float rstd = rsqrtf(var + 1e-5f);
  float4 gg = *(const float4*)(gn + tid * 4);
  float4 bb = *(const float4*)(bn + tid * 4);
  float4 o = { (x0 - mean) * rstd * gg.x + bb.x,
               (x1 - mean) * rstd * gg.y + bb.y,
               (x2 - mean) * rstd * gg.z + bb.z,
               (x3 - mean) * rstd * gg.w + bb.w };
  *(float4*)(out + (long)t * 1024 + tid * 4) = o;
}

// router pass 1: one wave per token; NO global atomics.
__global__ void router_compute(const float* __restrict__ x, const float* __restrict__ rw,
                               const float* __restrict__ rb,
                               int* __restrict__ top1, int* __restrict__ top2,
                               float* __restrict__ g1o, float* __restrict__ g2o,
                               float* __restrict__ partialP) {
  __shared__ float pp[4][8];
  int w = threadIdx.x >> 6, lane = threadIdx.x & 63;
  int t = blockIdx.x * 4 + w;
  const float* xp = x + (long)t * 1024;
  float xv[16];
#pragma unroll
  for (int i = 0; i < 16; ++i) xv[i] = xp[lane + i * 64];
  float logit[8];
#pragma unroll
  for (int e = 0; e < 8; ++e) {
    const float* wp = rw + e * 1024;
    double a = 0.0;
#pragma unroll
    for (int i = 0; i < 16; ++i) a += (double)xv[i] * (double)wp[lane + i * 64];
    for (int m = 1; m < 64; m <<= 1) a += __shfl_xor(a, m);
    logit[e] = (float)a + rb[e];
  }
  float mx = logit[0];
#pragma unroll
  for (int e = 1; e < 8; ++e) mx = fmaxf(mx, logit[e]);
  float pe[8], sum = 0.f;
#pragma unroll
  for (int e = 0; e < 8; ++e) { pe[e] = expf(logit[e] - mx); sum += pe[e]; }
  float inv = 1.f / sum;
#pragma unroll
  for (int e = 0; e < 8; ++e) pe[e] *= inv;
  int i1 = 0;
#pragma unroll
  for (int e = 1; e < 8; ++e) if (pe[e] > pe[i1]) i1 = e;
  int i2 = (i1 == 0) ? 1 : 0;
#pragma unroll
  for (int e = 0; e < 8; ++e) if (e != i1 && pe[e] > pe[i2]) i2 = e;
  float denom = pe[i1] + pe[i2];
  if (lane == 0) {
    top1[t] = i1; top2[t] = i2;
    g1o[t] = pe[i1] / denom; g2o[t] = pe[i2] / denom;
#pragma unroll
    for (int e = 0; e < 8; ++e) pp[w][e] = pe[e];
  }
  __syncthreads();
  if (threadIdx.x < 8) {
    partialP[(long)blockIdx.x * 8 + threadIdx.x] =
        pp[0][threadIdx.x] + pp[1][threadIdx.x] + pp[2][threadIdx.x] + pp[3][threadIdx.x];
  }
}

// router pass 2 (ONE block, 1024 threads): probsum reduce, counting-sort
// tokens into packed per-expert lists (contention-free), lb loss.
__global__ void __launch_bounds__(1024) router_finalize(
    const float* __restrict__ partialP,
    const int* __restrict__ top1, const int* __restrict__ top2,
    int* __restrict__ counts, int* __restrict__ eoff_out,
    int* __restrict__ tokList, int* __restrict__ pos1, int* __restrict__ pos2,
    float* __restrict__ lb_out) {
  __shared__ float redP[16][8];
  __shared__ int wtot[16][8];
  __shared__ int tot[8], eoff[8];
  __shared__ float psum[8];
  int tid = threadIdx.x;
  int lane = tid & 63, wv = tid >> 6;

  float p[8];
#pragma unroll
  for (int e = 0; e < 8; ++e) p[e] = partialP[(long)tid * 8 + e];
  for (int m = 1; m < 64; m <<= 1)
#pragma unroll
    for (int e = 0; e < 8; ++e) p[e] += __shfl_xor(p[e], m);
  if (lane == 0)
#pragma unroll
    for (int e = 0; e < 8; ++e) redP[wv][e] = p[e];

  int c[8] = {0, 0, 0, 0, 0, 0, 0, 0};
  int expid[8];
#pragma unroll
  for (int j = 0; j < 8; ++j) {
    int i = tid * 8 + j;
    int t = i >> 1;
    int e = (i & 1) ? top2[t] : top1[t];
    expid[j] = e;
    c[e]++;
  }
  int inc[8];
#pragma unroll
  for (int e = 0; e < 8; ++e) inc[e] = c[e];
  for (int d = 1; d < 64; d <<= 1) {
#pragma unroll
    for (int e = 0; e < 8; ++e) {
      int o = __shfl_up(inc[e], d);
      if (lane >= d) inc[e] += o;
    }
  }
  if (lane == 63)
#pragma unroll
    for (int e = 0; e < 8; ++e) wtot[wv][e] = inc[e];
  __syncthreads();
  if (tid < 8) {
    int run = 0;
#pragma unroll
    for (int w = 0; w < 16; ++w) { int v = wtot[w][tid]; wtot[w][tid] = run; run += v; }
    tot[tid] = run;
    float s = 0.f;
#pragma unroll
    for (int w = 0; w < 16; ++w) s += redP[w][tid];
    psum[tid] = s;
  }
  __syncthreads();
  if (tid == 0) {
    int off = 0;
#pragma unroll
    for (int e = 0; e < 8; ++e) { eoff[e] = off; off += tot[e]; }
  }
  __syncthreads();
  int base[8], c2[8] = {0, 0, 0, 0, 0, 0, 0, 0};
#pragma unroll
  for (int e = 0; e < 8; ++e) base[e] = eoff[e] + wtot[wv][e] + inc[e] - c[e];
#pragma unroll
  for (int j = 0; j < 8; ++j) {
    int i = tid * 8 + j;
    int t = i >> 1;
    int e = expid[j];
    int dest = base[e] + c2[e]++;
    tokList[dest] = t;
    if (i & 1) pos2[t] = dest; else pos1[t] = dest;
  }
  if (tid < 8) { counts[tid] = tot[tid]; eoff_out[tid] = eoff[tid]; }
  if (tid == 0) {
    float lb = 0.f;
#pragma unroll
    for (int e = 0; e < 8; ++e)
      lb += ((float)tot[e] / 8192.f) * (psum[e] / 4096.f);
    *lb_out = 8.f * lb;
  }
}

__global__ void sentinel_kernel(float* out, int n) {
  if (threadIdx.x == 0) { out[0] = 1e9f; out[n - 1] = 1e9f; }
}

// ---------------------------------------------------------------------------
extern "C" void kernel_launch(void* const* d_in, const int* in_sizes, int n_in,
                              void* d_out, int out_size, void* d_ws, size_t ws_size,
                              hipStream_t stream) {
  const float* src        = (const float*)d_in[0];
  const float* in_proj_w  = (const float*)d_in[1];
  const float* in_proj_b  = (const float*)d_in[2];
  const float* out_proj_w = (const float*)d_in[3];
  const float* out_proj_b = (const float*)d_in[4];
  const float* ln1_g      = (const float*)d_in[5];
  const float* ln1_b      = (const float*)d_in[6];
  const float* router_w   = (const float*)d_in[7];
  const float* router_b   = (const float*)d_in[8];
  const float* w1         = (const float*)d_in[9];
  const float* b1         = (const float*)d_in[10];
  const float* w2         = (const float*)d_in[11];
  const float* b2         = (const float*)d_in[12];
  const float* ln2_g      = (const float*)d_in[13];
  const float* ln2_b      = (const float*)d_in[14];
  float* out = (float*)d_out;

  char* ws = (char*)d_ws;
  size_t off = 0;
  auto alloc = [&](size_t bytes) -> char* {
    char* p = ws + off;
    off += (bytes + 255) & ~(size_t)255;
    return p;
  };
  // big block: Q/K/V hi+lo planes during attention; w1t/w2t after
  char*  blockW = alloc(8ll * (DFF * DMODEL + DMODEL * DFF) * 2);  // 128MB
  short* Qh = (short*)(blockW + 0ll  * 1024 * 1024);
  short* Ql = (short*)(blockW + 8ll  * 1024 * 1024);
  short* Kh = (short*)(blockW + 16ll * 1024 * 1024);
  short* Kl = (short*)(blockW + 24ll * 1024 * 1024);
  short* Vh = (short*)(blockW + 32ll * 1024 * 1024);
  short* Vl = (short*)(blockW + 40ll * 1024 * 1024);
  short* w1t = (short*)blockW;                                      // [E][dff][d]
  short* w2t = (short*)(blockW + 8ll * DFF * DMODEL * 2);           // [E][d][dff]
  short* winh  = (short*)alloc(3072ll * 1024 * 2);
  short* winl  = (short*)alloc(3072ll * 1024 * 2);
  short* wouth = (short*)alloc(1024ll * 1024 * 2);
  short* woutl = (short*)alloc(1024ll * 1024 * 2);
  short* xh    = (short*)alloc((long)TOKENS * DMODEL * 2);
  short* xl    = (short*)alloc((long)TOKENS * DMODEL * 2);
  char*  reg1  = alloc((long)TOKENS * 3072 * 4);     // 48MB: qkv f32 -> O planes/x1 -> y
  float* qkvf  = (float*)reg1;
  short* Ohi   = (short*)(reg1 + 16ll * 1024 * 1024);
  short* Olo   = (short*)(reg1 + 24ll * 1024 * 1024);
  float* x1    = (float*)(reg1 + 32ll * 1024 * 1024);
  float* y     = (float*)reg1;                       // packed expert outputs [8192,1024] f32
  char*  reg2  = alloc(16ll * 1024 * 1024 * 4);      // 64MB: h (bf16 [8192,4096])
  short* h      = (short*)reg2;
  short* x1nbf = (short*)alloc((long)TOKENS * DMODEL * 2);
  float* accum = (float*)alloc((long)TOKENS * DMODEL * 4);
  float* partialP = (float*)alloc(1024 * 8 * 4);
  int*   top1   = (int*)alloc(TOKENS * 4);
  int*   top2   = (int*)alloc(TOKENS * 4);
  float* g1a    = (float*)alloc(TOKENS * 4);
  float* g2a    = (float*)alloc(TOKENS * 4);
  int*   pos1   = (int*)alloc(TOKENS * 4);
  int*   pos2   = (int*)alloc(TOKENS * 4);
  int*   counts = (int*)alloc(32);
  int*   eoff   = (int*)alloc(32);
  int*   tokList = (int*)alloc(2 * TOKENS * 4);
  size_t needed = off;

  if (ws_size < needed) {
    sentinel_kernel<<<1, 64, 0, stream>>>(out, out_size);
    return;
  }

  // splits of f32 inputs
  split_bf16<<<3072 * 1024 / 1024, 256, 0, stream>>>(in_proj_w, winh, winl, 3072 * 1024);
  split_bf16<<<1024 * 1024 / 1024, 256, 0, stream>>>(out_proj_w, wouth, woutl, 1024 * 1024);
  split_bf16<<<TOKENS * DMODEL / 1024, 256, 0, stream>>>(src, xh, xl, TOKENS * DMODEL);

  // QKV projection (split): qkv f32 = x @ win^T + b
  gemm_nt<128, 128, 64, 64, 1, 0, false, true><<<dim3(32, 24, 1), 256, 0, stream>>>(
      xh, xl, 1024, 0, winh, winl, 1024, 0, qkvf, 3072, 0,
      TOKENS, 3072, 1024, 1.f, in_proj_b, 0, nullptr, nullptr, nullptr, nullptr);
  repack_qkv_split<<<(int)((long)TOKENS * 3072 / 256), 256, 0, stream>>>(qkvf, Qh, Ql, Kh, Kl, Vh, Vl);

  // fused flash attention: writes Ohi/Olo directly (qkvf region is dead)
  fused_attn<<<dim3(8, 1, 64), 256, 0, stream>>>(Qh, Ql, Kh, Kl, Vh, Vl, Ohi, Olo);

  // expert weight transposes now (blockW's Q/K/V no longer needed after attn)
  transpose_bf16<<<dim3(DFF / 64, DMODEL / 64, 8), 256, 0, stream>>>(w1, w1t, DMODEL, DFF);
  transpose_bf16<<<dim3(DMODEL / 64, DFF / 64, 8), 256, 0, stream>>>(w2, w2t, DFF, DMODEL);

  // out-projection (split) + bias + residual(src) -> x1 f32
  gemm_nt<128, 128, 64, 64, 1, 0, false, true><<<dim3(32, 8, 1), 256, 0, stream>>>(
      Ohi, Olo, 1024, 0, wouth, woutl, 1024, 0, x1, 1024, 0,
      TOKENS, 1024, 1024, 1.f, out_proj_b, 0, src, nullptr, nullptr, nullptr);

  // LN1 -> accum (f32 residual base) + x1nbf (bf16 expert input)
  ln_rows<<<TOKENS, 256, 0, stream>>>(x1, ln1_g, ln1_b, accum, x1nbf);

  // router (atomic-free)
  router_compute<<<TOKENS / 4, 256, 0, stream>>>(accum, router_w, router_b,
                                                 top1, top2, g1a, g2a, partialP);
  router_finalize<<<1, 1024, 0, stream>>>(partialP, top1, top2, counts, eoff,
                                          tokList, pos1, pos2, out + (out_size - 1));

  // expert GEMM1: h = relu(gather(x1nbf) @ w1t[e]^T + b1[e]) (packed bf16)
  gemm_nt<128, 128, 64, 64, 0, 1, true, false><<<dim3(32, 32, 8), 256, 0, stream>>>(
      x1nbf, nullptr, 1024, 0, w1t, nullptr, 1024, (long)DFF * DMODEL, h, DFF, 0,
      0, DFF, 1024, 1.f, b1, DFF, nullptr, tokList, counts, eoff);

  // expert GEMM2: y[packed] = h @ w2t[e]^T + b2[e]  (f32 store, no atomics)
  gemm_nt<128, 128, 64, 64, 1, 2, false, false><<<dim3(32, 8, 8), 256, 0, stream>>>(
      h, nullptr, DFF, 0, w2t, nullptr, DFF, (long)DMODEL * DFF, y, 1024, 0,
      0, DMODEL, DFF, 1.f, b2, DMODEL, nullptr, tokList, counts, eoff);

  // combine + LN2 -> final output
  combine_ln2<<<TOKENS, 256, 0, stream>>>(accum, y, pos1, pos2, g1a, g2a,
                                          ln2_g, ln2_b, out);
}